// Round 8
// baseline (426.806 us; speedup 1.0000x reference)
//
#include <hip/hip_runtime.h>
#include <stdint.h>
#include <stddef.h>

typedef unsigned short u16;
typedef uint32_t u32;
typedef __bf16 bf16x8 __attribute__((ext_vector_type(8)));
typedef float f32x4 __attribute__((ext_vector_type(4)));

#define DEV __device__ __forceinline__

// Async global->LDS, 16B per lane. HW writes wave-uniform-base + lane*16;
// our staging dests are exactly &X[tid*8] (u16) = base + lane*16B, so the
// linear layout is preserved. Counted in vmcnt; __syncthreads drains it.
#define GLD16(g, l) __builtin_amdgcn_global_load_lds( \
    (const __attribute__((address_space(1))) u32*)(g), \
    (__attribute__((address_space(3))) u32*)(l), 16, 0, 0)

DEV float bf2f(u16 u){ union{uint32_t i; float f;} c; c.i=(uint32_t)u<<16; return c.f; }
DEV u16 f2bf(float f){ union{float f; uint32_t i;} c; c.f=f; uint32_t x=c.i;
  uint32_t r = x + 0x7FFFu + ((x>>16)&1u); return (u16)(r>>16); }
DEV uint32_t fmap(float f){ union{float f; uint32_t u;} c; c.f=f;
  return (c.u & 0x80000000u) ? ~c.u : (c.u | 0x80000000u); }
DEV float funmap(uint32_t u){ union{uint32_t u; float f;} c;
  c.u = (u & 0x80000000u) ? (u & 0x7FFFFFFFu) : ~u; return c.f; }
DEV void split2(float x, u16& h, u16& l){ h = f2bf(x); l = f2bf(x - bf2f(h)); }

// ---- block reductions (256 threads = 4 waves) ----
DEV float bredsum(float v, float* buf, int tid){
  #pragma unroll
  for(int o=32;o;o>>=1) v += __shfl_down(v,o);
  __syncthreads();
  if((tid&63)==0) buf[tid>>6]=v;
  __syncthreads();
  return buf[0]+buf[1]+buf[2]+buf[3];
}
DEV float bredmax(float v, float* buf, int tid){
  #pragma unroll
  for(int o=32;o;o>>=1) v = fmaxf(v, __shfl_down(v,o));
  __syncthreads();
  if((tid&63)==0) buf[tid>>6]=v;
  __syncthreads();
  return fmaxf(fmaxf(buf[0],buf[1]),fmaxf(buf[2],buf[3]));
}
DEV int bredsumi(int v, int* buf, int tid){
  #pragma unroll
  for(int o=32;o;o>>=1) v += __shfl_down(v,o);
  __syncthreads();
  if((tid&63)==0) buf[tid>>6]=v;
  __syncthreads();
  return buf[0]+buf[1]+buf[2]+buf[3];
}

// ============================================================================
// 64x128-tile plain bf16 GEMM (small-M split-K cases). m97-style async staging.
// ============================================================================
template<bool RELU, int SK>
__global__ __launch_bounds__(256)
void gemm1_64(const u16* __restrict__ A, int lda,
              const u16* __restrict__ Bt, int ldb,
              const float* __restrict__ bias, float scale,
              u16* __restrict__ outb, float* __restrict__ outf,
              float* __restrict__ part,
              int K, int ldc, int M)
{
  __shared__ __align__(16) u16 As[64*32];
  __shared__ __align__(16) u16 Bs[128*32];
  const int tid = threadIdx.x, lane = tid&63, wave = tid>>6;
  const int m0 = blockIdx.y*64, n0 = blockIdx.x*128;
  const int wm = (wave>>1)*32, wn = (wave&1)*64;
  const int ml = lane&15, quad = lane>>4;
  const int ks = K / SK;
  const int kbeg = blockIdx.z * ks;
  const u16* pa  = A  + (size_t)(m0+(tid>>2))*lda + kbeg + (tid&3)*8;
  const u16* pb0 = Bt + (size_t)(n0+(tid>>2))*ldb + kbeg + (tid&3)*8;
  const u16* pb1 = Bt + (size_t)(n0+64+(tid>>2))*ldb + kbeg + (tid&3)*8;

  f32x4 acc[2][4];
  #pragma unroll
  for(int i=0;i<2;i++)
    #pragma unroll
    for(int j=0;j<4;j++) acc[i][j] = (f32x4){0.f,0.f,0.f,0.f};

  for(int k0=0;k0<ks;k0+=32){
    __syncthreads();                 // prior reads done before overwrite
    GLD16(pa +k0, &As[tid*8]);
    GLD16(pb0+k0, &Bs[tid*8]);
    GLD16(pb1+k0, &Bs[(256+tid)*8]);
    __syncthreads();                 // drains vmcnt -> LDS ready
    bf16x8 af[2], bf[4];
    #pragma unroll
    for(int mi=0;mi<2;mi++) af[mi] = *(const bf16x8*)&As[(wm+mi*16+ml)*32 + quad*8];
    #pragma unroll
    for(int ni=0;ni<4;ni++) bf[ni] = *(const bf16x8*)&Bs[(wn+ni*16+ml)*32 + quad*8];
    #pragma unroll
    for(int mi=0;mi<2;mi++)
      #pragma unroll
      for(int ni=0;ni<4;ni++)
        acc[mi][ni] = __builtin_amdgcn_mfma_f32_16x16x32_bf16(af[mi], bf[ni], acc[mi][ni], 0,0,0);
  }
  // C/D: col = lane&15, row = quad*4 + reg  (m89-verified)
  #pragma unroll
  for(int mi=0;mi<2;mi++){
    const int rbase = m0 + wm + mi*16 + quad*4;
    #pragma unroll
    for(int ni=0;ni<4;ni++){
      const int col = n0 + wn + ni*16 + ml;
      if(SK==1){
        const float bv = bias ? bias[col] : 0.f;
        #pragma unroll
        for(int r=0;r<4;r++){
          float v = acc[mi][ni][r]*scale + bv;
          if(RELU) v = fmaxf(v, 0.f);
          const size_t idx = (size_t)(rbase + r)*ldc + col;
          if(outb) outb[idx] = f2bf(v);
          if(outf) outf[idx] = v;
        }
      }else{
        #pragma unroll
        for(int r=0;r<4;r++)
          part[((size_t)blockIdx.z*M + rbase + r)*ldc + col] = acc[mi][ni][r];
      }
    }
  }
}

// ============================================================================
// 128x128-tile plain bf16 GEMM. 4 waves, each 64x64 (acc[4][4]). Async staging.
// ============================================================================
template<bool RELU>
__global__ __launch_bounds__(256)
void gemm1_128(const u16* __restrict__ A, int lda,
               const u16* __restrict__ Bt, int ldb,
               const float* __restrict__ bias, float scale,
               u16* __restrict__ outb, float* __restrict__ outf,
               int K, int ldc)
{
  __shared__ __align__(16) u16 As[128*32];
  __shared__ __align__(16) u16 Bs[128*32];
  const int tid = threadIdx.x, lane = tid&63, wave = tid>>6;
  const int m0 = blockIdx.y*128, n0 = blockIdx.x*128;
  const int wm = (wave>>1)*64, wn = (wave&1)*64;
  const int ml = lane&15, quad = lane>>4;
  const u16* pa0 = A  + (size_t)(m0+(tid>>2))*lda    + (tid&3)*8;
  const u16* pa1 = A  + (size_t)(m0+64+(tid>>2))*lda + (tid&3)*8;
  const u16* pb0 = Bt + (size_t)(n0+(tid>>2))*ldb    + (tid&3)*8;
  const u16* pb1 = Bt + (size_t)(n0+64+(tid>>2))*ldb + (tid&3)*8;

  f32x4 acc[4][4];
  #pragma unroll
  for(int i=0;i<4;i++)
    #pragma unroll
    for(int j=0;j<4;j++) acc[i][j] = (f32x4){0.f,0.f,0.f,0.f};

  for(int k0=0;k0<K;k0+=32){
    __syncthreads();
    GLD16(pa0+k0, &As[tid*8]);
    GLD16(pa1+k0, &As[(256+tid)*8]);
    GLD16(pb0+k0, &Bs[tid*8]);
    GLD16(pb1+k0, &Bs[(256+tid)*8]);
    __syncthreads();
    bf16x8 af[4], bf[4];
    #pragma unroll
    for(int mi=0;mi<4;mi++) af[mi] = *(const bf16x8*)&As[(wm+mi*16+ml)*32 + quad*8];
    #pragma unroll
    for(int ni=0;ni<4;ni++) bf[ni] = *(const bf16x8*)&Bs[(wn+ni*16+ml)*32 + quad*8];
    #pragma unroll
    for(int mi=0;mi<4;mi++)
      #pragma unroll
      for(int ni=0;ni<4;ni++)
        acc[mi][ni] = __builtin_amdgcn_mfma_f32_16x16x32_bf16(af[mi], bf[ni], acc[mi][ni], 0,0,0);
  }
  #pragma unroll
  for(int mi=0;mi<4;mi++){
    const int rbase = m0 + wm + mi*16 + quad*4;
    #pragma unroll
    for(int ni=0;ni<4;ni++){
      const int col = n0 + wn + ni*16 + ml;
      const float bv = bias ? bias[col] : 0.f;
      #pragma unroll
      for(int r=0;r<4;r++){
        float v = acc[mi][ni][r]*scale + bv;
        if(RELU) v = fmaxf(v, 0.f);
        const size_t idx = (size_t)(rbase + r)*ldc + col;
        if(outb) outb[idx] = f2bf(v);
        if(outf) outf[idx] = v;
      }
    }
  }
}

// ============================================================================
// Fused k|v GEMM: B = [WkT ; WvT] stacked (2048 rows). col<1024 -> kb (+bk),
// else -> vb (+bv). Both RELU. Async staging.
// ============================================================================
__global__ __launch_bounds__(256)
void gemm_kv_128(const u16* __restrict__ A, int lda,
                 const u16* __restrict__ Bt, int ldb,
                 const float* __restrict__ bk, const float* __restrict__ bv,
                 u16* __restrict__ kb, u16* __restrict__ vb, int K)
{
  __shared__ __align__(16) u16 As[128*32];
  __shared__ __align__(16) u16 Bs[128*32];
  const int tid = threadIdx.x, lane = tid&63, wave = tid>>6;
  const int m0 = blockIdx.y*128, n0 = blockIdx.x*128;
  const int wm = (wave>>1)*64, wn = (wave&1)*64;
  const int ml = lane&15, quad = lane>>4;
  const u16* pa0 = A  + (size_t)(m0+(tid>>2))*lda    + (tid&3)*8;
  const u16* pa1 = A  + (size_t)(m0+64+(tid>>2))*lda + (tid&3)*8;
  const u16* pb0 = Bt + (size_t)(n0+(tid>>2))*ldb    + (tid&3)*8;
  const u16* pb1 = Bt + (size_t)(n0+64+(tid>>2))*ldb + (tid&3)*8;

  f32x4 acc[4][4];
  #pragma unroll
  for(int i=0;i<4;i++)
    #pragma unroll
    for(int j=0;j<4;j++) acc[i][j] = (f32x4){0.f,0.f,0.f,0.f};

  for(int k0=0;k0<K;k0+=32){
    __syncthreads();
    GLD16(pa0+k0, &As[tid*8]);
    GLD16(pa1+k0, &As[(256+tid)*8]);
    GLD16(pb0+k0, &Bs[tid*8]);
    GLD16(pb1+k0, &Bs[(256+tid)*8]);
    __syncthreads();
    bf16x8 af[4], bf[4];
    #pragma unroll
    for(int mi=0;mi<4;mi++) af[mi] = *(const bf16x8*)&As[(wm+mi*16+ml)*32 + quad*8];
    #pragma unroll
    for(int ni=0;ni<4;ni++) bf[ni] = *(const bf16x8*)&Bs[(wn+ni*16+ml)*32 + quad*8];
    #pragma unroll
    for(int mi=0;mi<4;mi++)
      #pragma unroll
      for(int ni=0;ni<4;ni++)
        acc[mi][ni] = __builtin_amdgcn_mfma_f32_16x16x32_bf16(af[mi], bf[ni], acc[mi][ni], 0,0,0);
  }
  #pragma unroll
  for(int mi=0;mi<4;mi++){
    const int rbase = m0 + wm + mi*16 + quad*4;
    #pragma unroll
    for(int ni=0;ni<4;ni++){
      const int col = n0 + wn + ni*16 + ml;      // 0..2047
      const bool isv = col >= 1024;
      const int c2 = col & 1023;
      const float bb = isv ? bv[c2] : bk[c2];
      u16* outp = isv ? vb : kb;
      #pragma unroll
      for(int r=0;r<4;r++){
        const float v = fmaxf(acc[mi][ni][r] + bb, 0.f);
        outp[(size_t)(rbase + r)*1024 + c2] = f2bf(v);
      }
    }
  }
}

// ============================================================================
// 64x128-tile split-bf16 GEMM (small-M split-K cases). Async staging.
// ============================================================================
template<bool RELU, int SK>
__global__ __launch_bounds__(256)
void gemm3_64(const u16* __restrict__ Ah, const u16* __restrict__ Al, int lda,
              const u16* __restrict__ Bh, const u16* __restrict__ Bl, int ldb,
              const float* __restrict__ bias, float scale,
              u16* __restrict__ outh, u16* __restrict__ outl,
              float* __restrict__ outf, float* __restrict__ part,
              int K, int ldc, int M)
{
  __shared__ __align__(16) u16 AsH[64*32];
  __shared__ __align__(16) u16 AsL[64*32];
  __shared__ __align__(16) u16 BsH[128*32];
  __shared__ __align__(16) u16 BsL[128*32];
  const int tid = threadIdx.x, lane = tid&63, wave = tid>>6;
  const int m0 = blockIdx.y*64, n0 = blockIdx.x*128;
  const int wm = (wave>>1)*32, wn = (wave&1)*64;
  const int ml = lane&15, quad = lane>>4;
  const int ks = K / SK;
  const int kbeg = blockIdx.z * ks;
  const size_t ao  = (size_t)(m0+(tid>>2))*lda + kbeg + (tid&3)*8;
  const size_t bo0 = (size_t)(n0+(tid>>2))*ldb + kbeg + (tid&3)*8;
  const size_t bo1 = (size_t)(n0+64+(tid>>2))*ldb + kbeg + (tid&3)*8;

  f32x4 acc[2][4];
  #pragma unroll
  for(int i=0;i<2;i++)
    #pragma unroll
    for(int j=0;j<4;j++) acc[i][j] = (f32x4){0.f,0.f,0.f,0.f};

  for(int k0=0;k0<ks;k0+=32){
    __syncthreads();
    GLD16(Ah+ao +k0, &AsH[tid*8]);
    GLD16(Al+ao +k0, &AsL[tid*8]);
    GLD16(Bh+bo0+k0, &BsH[tid*8]);
    GLD16(Bl+bo0+k0, &BsL[tid*8]);
    GLD16(Bh+bo1+k0, &BsH[(256+tid)*8]);
    GLD16(Bl+bo1+k0, &BsL[(256+tid)*8]);
    __syncthreads();
    bf16x8 afh[2], afl[2], bfh[4], bfl[4];
    #pragma unroll
    for(int mi=0;mi<2;mi++){
      const int o = (wm+mi*16+ml)*32 + quad*8;
      afh[mi] = *(const bf16x8*)&AsH[o];
      afl[mi] = *(const bf16x8*)&AsL[o];
    }
    #pragma unroll
    for(int ni=0;ni<4;ni++){
      const int o = (wn+ni*16+ml)*32 + quad*8;
      bfh[ni] = *(const bf16x8*)&BsH[o];
      bfl[ni] = *(const bf16x8*)&BsL[o];
    }
    #pragma unroll
    for(int mi=0;mi<2;mi++)
      #pragma unroll
      for(int ni=0;ni<4;ni++){
        acc[mi][ni] = __builtin_amdgcn_mfma_f32_16x16x32_bf16(afh[mi], bfh[ni], acc[mi][ni], 0,0,0);
        acc[mi][ni] = __builtin_amdgcn_mfma_f32_16x16x32_bf16(afh[mi], bfl[ni], acc[mi][ni], 0,0,0);
        acc[mi][ni] = __builtin_amdgcn_mfma_f32_16x16x32_bf16(afl[mi], bfh[ni], acc[mi][ni], 0,0,0);
      }
  }
  #pragma unroll
  for(int mi=0;mi<2;mi++){
    const int rbase = m0 + wm + mi*16 + quad*4;
    #pragma unroll
    for(int ni=0;ni<4;ni++){
      const int col = n0 + wn + ni*16 + ml;
      if(SK==1){
        const float bv = bias ? bias[col] : 0.f;
        #pragma unroll
        for(int r=0;r<4;r++){
          float v = acc[mi][ni][r]*scale + bv;
          if(RELU) v = fmaxf(v, 0.f);
          const size_t idx = (size_t)(rbase + r)*ldc + col;
          if(outh){ u16 h, l; split2(v, h, l); outh[idx] = h; outl[idx] = l; }
          if(outf) outf[idx] = v;
        }
      }else{
        #pragma unroll
        for(int r=0;r<4;r++)
          part[((size_t)blockIdx.z*M + rbase + r)*ldc + col] = acc[mi][ni][r];
      }
    }
  }
}

// ============================================================================
// 128x128-tile split-bf16 GEMM (fp32-class). 4 waves x 64x64. Async staging.
// ============================================================================
__global__ __launch_bounds__(256)
void gemm3_128(const u16* __restrict__ Ah, const u16* __restrict__ Al, int lda,
               const u16* __restrict__ Bh, const u16* __restrict__ Bl, int ldb,
               const float* __restrict__ bias, float scale,
               float* __restrict__ outf, int K, int ldc)
{
  __shared__ __align__(16) u16 AsH[128*32];
  __shared__ __align__(16) u16 AsL[128*32];
  __shared__ __align__(16) u16 BsH[128*32];
  __shared__ __align__(16) u16 BsL[128*32];
  const int tid = threadIdx.x, lane = tid&63, wave = tid>>6;
  const int m0 = blockIdx.y*128, n0 = blockIdx.x*128;
  const int wm = (wave>>1)*64, wn = (wave&1)*64;
  const int ml = lane&15, quad = lane>>4;
  const size_t ao0 = (size_t)(m0+(tid>>2))*lda    + (tid&3)*8;
  const size_t ao1 = (size_t)(m0+64+(tid>>2))*lda + (tid&3)*8;
  const size_t bo0 = (size_t)(n0+(tid>>2))*ldb    + (tid&3)*8;
  const size_t bo1 = (size_t)(n0+64+(tid>>2))*ldb + (tid&3)*8;

  f32x4 acc[4][4];
  #pragma unroll
  for(int i=0;i<4;i++)
    #pragma unroll
    for(int j=0;j<4;j++) acc[i][j] = (f32x4){0.f,0.f,0.f,0.f};

  for(int k0=0;k0<K;k0+=32){
    __syncthreads();
    GLD16(Ah+ao0+k0, &AsH[tid*8]);
    GLD16(Ah+ao1+k0, &AsH[(256+tid)*8]);
    GLD16(Al+ao0+k0, &AsL[tid*8]);
    GLD16(Al+ao1+k0, &AsL[(256+tid)*8]);
    GLD16(Bh+bo0+k0, &BsH[tid*8]);
    GLD16(Bh+bo1+k0, &BsH[(256+tid)*8]);
    GLD16(Bl+bo0+k0, &BsL[tid*8]);
    GLD16(Bl+bo1+k0, &BsL[(256+tid)*8]);
    __syncthreads();
    bf16x8 afh[4], afl[4], bfh[4], bfl[4];
    #pragma unroll
    for(int mi=0;mi<4;mi++){
      const int o = (wm+mi*16+ml)*32 + quad*8;
      afh[mi] = *(const bf16x8*)&AsH[o];
      afl[mi] = *(const bf16x8*)&AsL[o];
    }
    #pragma unroll
    for(int ni=0;ni<4;ni++){
      const int o = (wn+ni*16+ml)*32 + quad*8;
      bfh[ni] = *(const bf16x8*)&BsH[o];
      bfl[ni] = *(const bf16x8*)&BsL[o];
    }
    #pragma unroll
    for(int mi=0;mi<4;mi++)
      #pragma unroll
      for(int ni=0;ni<4;ni++){
        acc[mi][ni] = __builtin_amdgcn_mfma_f32_16x16x32_bf16(afh[mi], bfh[ni], acc[mi][ni], 0,0,0);
        acc[mi][ni] = __builtin_amdgcn_mfma_f32_16x16x32_bf16(afh[mi], bfl[ni], acc[mi][ni], 0,0,0);
        acc[mi][ni] = __builtin_amdgcn_mfma_f32_16x16x32_bf16(afl[mi], bfh[ni], acc[mi][ni], 0,0,0);
      }
  }
  #pragma unroll
  for(int mi=0;mi<4;mi++){
    const int rbase = m0 + wm + mi*16 + quad*4;
    #pragma unroll
    for(int ni=0;ni<4;ni++){
      const int col = n0 + wn + ni*16 + ml;
      const float bv = bias ? bias[col] : 0.f;
      #pragma unroll
      for(int r=0;r<4;r++){
        const float v = acc[mi][ni][r]*scale + bv;
        outf[(size_t)(rbase + r)*ldc + col] = v;
      }
    }
  }
}

// ============================================================================
// reduce SK fp32 partials + bias/act -> split-bf16 / bf16 / fp32 outputs.
// Optional fused row-dot: bvout[row] = dot(bqv, rowvals)/32 (block == 1 row,
// valid when N==1024). Saves the separate bias_v launch.
// ============================================================================
template<bool RELU, int SK>
__global__ __launch_bounds__(256)
void reduce_epi(const float* __restrict__ part, const float* __restrict__ bias,
                float scale, u16* __restrict__ outh, u16* __restrict__ outl,
                u16* __restrict__ outb, float* __restrict__ outf,
                size_t MN, int N,
                const float* __restrict__ bqv, float* __restrict__ bvout)
{
  __shared__ float buf[4];
  const int tid = threadIdx.x;
  const size_t i = ((size_t)blockIdx.x*256 + tid)*4;
  float4 s = *(const float4*)(part + i);
  #pragma unroll
  for(int z=1; z<SK; z++){
    const float4 t = *(const float4*)(part + (size_t)z*MN + i);
    s.x += t.x; s.y += t.y; s.z += t.z; s.w += t.w;
  }
  const int col = (int)(i % (size_t)N);
  float4 bv = bias ? *(const float4*)(bias + col) : (float4){0.f,0.f,0.f,0.f};
  float v[4] = { s.x*scale + bv.x, s.y*scale + bv.y, s.z*scale + bv.z, s.w*scale + bv.w };
  if(RELU){
    #pragma unroll
    for(int j=0;j<4;j++) v[j] = fmaxf(v[j], 0.f);
  }
  if(outh){
    ushort4 h4, l4;
    split2(v[0], h4.x, l4.x); split2(v[1], h4.y, l4.y);
    split2(v[2], h4.z, l4.z); split2(v[3], h4.w, l4.w);
    *(ushort4*)(outh + i) = h4;
    *(ushort4*)(outl + i) = l4;
  }
  if(outb){
    ushort4 b4;
    b4.x=f2bf(v[0]); b4.y=f2bf(v[1]); b4.z=f2bf(v[2]); b4.w=f2bf(v[3]);
    *(ushort4*)(outb + i) = b4;
  }
  if(outf) *(float4*)(outf + i) = (float4){v[0],v[1],v[2],v[3]};
  if(bvout){   // uniform branch; block == one row (N==1024, 256 thr x 4)
    const float4 q = *(const float4*)(bqv + col);
    float d = q.x*v[0] + q.y*v[1] + q.z*v[2] + q.w*v[3];
    d = bredsum(d, buf, tid);
    if(tid==0) bvout[blockIdx.x] = d * 0.03125f;
  }
}

// ============================================================================
// Fused weight prep: all transposes + split conversions in ONE launch.
// ============================================================================
DEV void dev_tsplit(const float* in, u16* oh, u16* ol, int R, int C,
                    int bx, int by, int tid, float (*tile)[33])
{
  const int tx = tid & 31, ty = tid >> 5;
  #pragma unroll
  for(int i=0;i<32;i+=8)
    tile[ty+i][tx] = in[(size_t)(by*32+ty+i)*C + bx*32 + tx];
  __syncthreads();
  #pragma unroll
  for(int i=0;i<32;i+=8){
    const float v = tile[tx][ty+i];
    u16 h, l; split2(v, h, l);
    const size_t o = (size_t)(bx*32+ty+i)*R + by*32 + tx;
    oh[o] = h; if(ol) ol[o] = l;
  }
}
__global__ __launch_bounds__(256)
void prep_weights(const float* __restrict__ Wk, const float* __restrict__ W1,
                  const float* __restrict__ W2, const float* __restrict__ Wv,
                  const float* __restrict__ Wq,
                  u16* __restrict__ WkvTh, u16* __restrict__ WkTl,
                  u16* __restrict__ W1Th,  u16* __restrict__ W1Tl,
                  u16* __restrict__ W2Th,  u16* __restrict__ W2Tl,
                  u16* __restrict__ WqTh,
                  u16* __restrict__ Wqh,   u16* __restrict__ Wql)
{
  __shared__ float tile[32][33];
  const int id = blockIdx.x, tid = threadIdx.x;
  if(id < 1024){
    dev_tsplit(Wk, WkvTh, WkTl, 1024, 1024, id&31, id>>5, tid, tile);
  }else if(id < 3072){
    const int l = id - 1024;
    dev_tsplit(W1, W1Th, W1Tl, 2048, 1024, l&31, l>>5, tid, tile);
  }else if(id < 4096){
    const int l = id - 3072;
    dev_tsplit(W2, W2Th, W2Tl, 1024, 1024, l&31, l>>5, tid, tile);
  }else if(id < 5120){
    const int l = id - 4096;
    dev_tsplit(Wv, WkvTh + 1024*1024, nullptr, 1024, 1024, l&31, l>>5, tid, tile);
  }else if(id < 6144){
    const int l = id - 5120;
    dev_tsplit(Wq, WqTh, nullptr, 1024, 1024, l&31, l>>5, tid, tile);
  }else{
    const int l = id - 6144;
    const int i = l*256 + tid;
    const float4 v = ((const float4*)Wq)[i];
    ushort4 h4, l4;
    split2(v.x, h4.x, l4.x); split2(v.y, h4.y, l4.y);
    split2(v.z, h4.z, l4.z); split2(v.w, h4.w, l4.w);
    ((ushort4*)Wqh)[i] = h4; ((ushort4*)Wql)[i] = l4;
  }
}

// ============================================================================
// Fused LayerNorms: blocks [0,8192) = input rows -> xh/xl (stride 1024);
// blocks [8192,8704) = edge rows (mu + exp(lsig)*noise) -> cath/catl (2048).
// ============================================================================
__global__ __launch_bounds__(256)
void ln_all(const float* __restrict__ in, const float* __restrict__ g,
            const float* __restrict__ bb, u16* __restrict__ outh,
            u16* __restrict__ outl,
            const float* __restrict__ noise, const float* __restrict__ mu,
            const float* __restrict__ lsig, const float* __restrict__ ge,
            const float* __restrict__ be, u16* __restrict__ cath,
            u16* __restrict__ catl)
{
  __shared__ float buf[4];
  const int tid = threadIdx.x;
  const bool edge = blockIdx.x >= 8192;
  const int row = edge ? (blockIdx.x - 8192) : blockIdx.x;
  float v0,v1,v2,v3;
  if(!edge){
    const float4 xv = ((const float4*)(in + (size_t)row*1024))[tid];
    v0=xv.x; v1=xv.y; v2=xv.z; v3=xv.w;
  }else{
    const float4 nv  = ((const float4*)(noise + (size_t)row*1024))[tid];
    const float4 muv = ((const float4*)mu)[tid];
    const float4 lsv = ((const float4*)lsig)[tid];
    v0 = muv.x + expf(lsv.x)*nv.x;
    v1 = muv.y + expf(lsv.y)*nv.y;
    v2 = muv.z + expf(lsv.z)*nv.z;
    v3 = muv.w + expf(lsv.w)*nv.w;
  }
  float s  = bredsum(v0+v1+v2+v3, buf, tid);
  float s2 = bredsum(v0*v0+v1*v1+v2*v2+v3*v3, buf, tid);
  const float mean = s * (1.f/1024.f);
  const float var  = s2 * (1.f/1024.f) - mean*mean;
  const float rs   = 1.f / sqrtf(var + 1e-5f);
  const float4 gv = ((const float4*)(edge?ge:g))[tid];
  const float4 bv = ((const float4*)(edge?be:bb))[tid];
  float o0 = (v0-mean)*rs*gv.x + bv.x;
  float o1 = (v1-mean)*rs*gv.y + bv.y;
  float o2 = (v2-mean)*rs*gv.z + bv.z;
  float o3 = (v3-mean)*rs*gv.w + bv.w;
  ushort4 oh, ol;
  split2(o0, oh.x, ol.x); split2(o1, oh.y, ol.y);
  split2(o2, oh.z, ol.z); split2(o3, oh.w, ol.w);
  u16* ph = edge ? cath : outh;
  u16* pl = edge ? catl : outl;
  const int ostride = edge ? 2048 : 1024;
  ((ushort4*)(ph + (size_t)row*ostride))[tid] = oh;
  ((ushort4*)(pl + (size_t)row*ostride))[tid] = ol;
}

// ============================================================================
// softmax(8192)+eps+renorm + top-k_n -> (idx, weight) pairs. 1 block/row.
// ============================================================================
#define SWZ(i) ((i) ^ (((((unsigned)(i))>>5)&7u)<<2))
__global__ __launch_bounds__(256)
void softmax_topk_a(const float* __restrict__ dots, const int* __restrict__ knp,
                    int* __restrict__ tidx, float* __restrict__ tw)
{
  const int NC = 8192;
  __shared__ __align__(16) uint32_t us[8192];
  __shared__ float fbuf[4];
  __shared__ int ibuf[4];
  __shared__ int scan[256];
  __shared__ uint32_t hist[256];
  __shared__ uint32_t bcast;
  __shared__ int slot_ctr;
  const int row = blockIdx.x, tid = threadIdx.x;
  const int lane = tid & 63, wave = tid >> 6;
  const float* x = dots + (size_t)row * NC;

  float mx = -3.4e38f;
  #pragma unroll
  for(int it=0; it<8; ++it){
    const int i = (tid + it*256)*4;
    const float4 f = *(const float4*)(x + i);
    mx = fmaxf(fmaxf(mx, fmaxf(f.x,f.y)), fmaxf(f.z,f.w));
    uint4 u; u.x=fmap(f.x); u.y=fmap(f.y); u.z=fmap(f.z); u.w=fmap(f.w);
    *(uint4*)&us[SWZ(i)] = u;
  }
  mx = bredmax(mx, fbuf, tid);

  float se = 0.f;
  #pragma unroll
  for(int it=0; it<8; ++it){
    const int i = (tid + it*256)*4;
    const uint4 u = *(const uint4*)&us[SWZ(i)];
    se += expf(funmap(u.x)-mx) + expf(funmap(u.y)-mx)
        + expf(funmap(u.z)-mx) + expf(funmap(u.w)-mx);
  }
  se = bredsum(se, fbuf, tid);
  const float T = 1.f + (float)NC * 1e-8f;

  const int k = knp[0];
  const int base = tid*32;

  uint32_t prefix = 0;
  int remaining = k;
  #pragma unroll
  for(int shift=24; shift>=0; shift-=8){
    hist[tid] = 0;
    __syncthreads();
    const uint32_t himask = (shift==24) ? 0u : (0xFFFFFFFFu << (shift+8));
    #pragma unroll
    for(int j=0;j<32;j+=4){
      const uint4 u4 = *(const uint4*)&us[SWZ(base+j)];
      const uint32_t uu[4] = {u4.x,u4.y,u4.z,u4.w};
      #pragma unroll
      for(int t=0;t<4;t++)
        if((uu[t] & himask) == prefix) atomicAdd(&hist[(uu[t]>>shift)&255u], 1u);
    }
    __syncthreads();
    if(wave==0){
      const uint32_t h0=hist[4*lane], h1=hist[4*lane+1],
                     h2=hist[4*lane+2], h3=hist[4*lane+3];
      const uint32_t s3=h3, s2=h2+s3, s1=h1+s2, s0=h0+s1;
      uint32_t tsum = s0;
      #pragma unroll
      for(int o=1;o<64;o<<=1){
        const uint32_t vv = __shfl_down(tsum, o);
        if(lane + o < 64) tsum += vv;
      }
      const uint32_t excl = tsum - s0;
      const uint32_t r = (uint32_t)remaining;
      int cand = -1; uint32_t gsel = 0;
      if     (s3+excl >= r){ cand = 4*lane+3; gsel = excl; }
      else if(s2+excl >= r){ cand = 4*lane+2; gsel = s3+excl; }
      else if(s1+excl >= r){ cand = 4*lane+1; gsel = s2+excl; }
      else if(s0+excl >= r){ cand = 4*lane+0; gsel = s1+excl; }
      int bestc = cand; uint32_t bestg = gsel;
      #pragma unroll
      for(int o=32;o;o>>=1){
        const int oc = __shfl_xor(bestc, o);
        const uint32_t og = __shfl_xor(bestg, o);
        if(oc > bestc){ bestc = oc; bestg = og; }
      }
      if(lane==0) bcast = (uint32_t)bestc;
      remaining -= (int)bestg;
    }
    __syncthreads();
    prefix |= bcast << shift;
  }
  const uint32_t uth = prefix;

  int gt = 0, eq = 0;
  #pragma unroll
  for(int j=0;j<32;j+=4){
    const uint4 u4 = *(const uint4*)&us[SWZ(base+j)];
    gt += (u4.x>uth)+(u4.y>uth)+(u4.z>uth)+(u4.w>uth);
    eq += (u4.x==uth)+(u4.y==uth)+(u4.z==uth)+(u4.w==uth);
  }
  const int c1 = bredsumi(gt, ibuf, tid);
  __syncthreads();
  scan[tid] = eq;
  __syncthreads();
  #pragma unroll
  for(int o=1;o<256;o<<=1){
    int t = (tid>=o) ? scan[tid-o] : 0;
    __syncthreads();
    scan[tid] += t;
    __syncthreads();
  }
  int eq_rank = scan[tid] - eq;
  const int budget = k - c1;
  if(tid==0) slot_ctr = 0;
  __syncthreads();
  #pragma unroll 2
  for(int j=0;j<32;j+=4){
    const uint4 u4 = *(const uint4*)&us[SWZ(base+j)];
    const uint32_t uu[4] = {u4.x,u4.y,u4.z,u4.w};
    #pragma unroll
    for(int t=0;t<4;t++){
      const uint32_t u = uu[t];
      bool sel = (u > uth);
      if(u == uth){ sel = (eq_rank < budget); eq_rank++; }
      if(sel){
        const int s = atomicAdd(&slot_ctr, 1);
        const float f = funmap(u);
        const float w = (expf(f - mx)/se + 1e-8f) / T;
        if(s < 128){ tidx[row*128 + s] = base + j + t; tw[row*128 + s] = w; }
      }
    }
  }
}

// updates[row] = sum_j w_j * v[idx_j] (v bf16) ; split-bf16 into cat[:,1024:]
__global__ __launch_bounds__(256)
void gather_updates(const int* __restrict__ tidx, const float* __restrict__ tw,
                    const int* __restrict__ knp, const u16* __restrict__ v,
                    u16* __restrict__ cath, u16* __restrict__ catl)
{
  __shared__ int   idx_s[128];
  __shared__ float w_s[128];
  const int row = blockIdx.x, tid = threadIdx.x;
  const int kk = knp[0];
  if(tid < 128){
    idx_s[tid] = (tid < kk) ? (tidx[row*128+tid] & 8191) : 0;
    w_s[tid]   = (tid < kk) ? tw[row*128+tid] : 0.f;
  }
  __syncthreads();
  const int c = tid*4;
  float a0=0,a1=0,a2=0,a3=0;
  for(int j=0;j<kk && j<128;j++){
    const ushort4 vv = *(const ushort4*)&v[(size_t)idx_s[j]*1024 + c];
    const float w = w_s[j];
    a0 += w*bf2f(vv.x); a1 += w*bf2f(vv.y); a2 += w*bf2f(vv.z); a3 += w*bf2f(vv.w);
  }
  ushort4 oh, ol;
  split2(a0, oh.x, ol.x); split2(a1, oh.y, ol.y);
  split2(a2, oh.z, ol.z); split2(a3, oh.w, ol.w);
  ((ushort4*)(cath + (size_t)row*2048 + 1024))[tid] = oh;
  ((ushort4*)(catl + (size_t)row*2048 + 1024))[tid] = ol;
}

// ============================================================================
// H: softmax over 512 + top-k_e mask, one WAVE per row (4 rows/block).
// ============================================================================
__global__ __launch_bounds__(256)
void softmax_topk_h_wave(const float* __restrict__ dv, const int* __restrict__ kep,
                         float* __restrict__ H)
{
  const int wave = threadIdx.x >> 6, lane = threadIdx.x & 63;
  const int row = blockIdx.x*4 + wave;
  const float* x = dv + (size_t)row*512 + lane*8;
  const float4 a = *(const float4*)x;
  const float4 b = *(const float4*)(x+4);
  float vals[8] = {a.x,a.y,a.z,a.w,b.x,b.y,b.z,b.w};

  float mx = vals[0];
  #pragma unroll
  for(int j=1;j<8;j++) mx = fmaxf(mx, vals[j]);
  #pragma unroll
  for(int o=32;o;o>>=1) mx = fmaxf(mx, __shfl_xor(mx, o));
  float e[8], se = 0.f;
  #pragma unroll
  for(int j=0;j<8;j++){ e[j] = expf(vals[j]-mx); se += e[j]; }
  #pragma unroll
  for(int o=32;o;o>>=1) se += __shfl_xor(se, o);
  const float inv = 1.f/se;

  const int k = kep[0];
  unsigned int selmask = 0;
  for(int r=0;r<k;r++){
    unsigned long long best = 0;
    #pragma unroll
    for(int j=0;j<8;j++){
      if(!((selmask>>j)&1u)){
        const unsigned long long key =
          ((unsigned long long)fmap(vals[j]) << 9) | (unsigned long long)(511 - (lane*8+j));
        if(key > best) best = key;
      }
    }
    #pragma unroll
    for(int o=32;o;o>>=1){
      const unsigned long long other = __shfl_xor(best, o);
      if(other > best) best = other;
    }
    const int bidx = 511 - (int)(best & 511ull);
    if((bidx>>3) == lane) selmask |= 1u << (bidx & 7);
  }

  float4 o0, o1;
  o0.x = (selmask&  1u) ? e[0]*inv : 0.f;
  o0.y = (selmask&  2u) ? e[1]*inv : 0.f;
  o0.z = (selmask&  4u) ? e[2]*inv : 0.f;
  o0.w = (selmask&  8u) ? e[3]*inv : 0.f;
  o1.x = (selmask& 16u) ? e[4]*inv : 0.f;
  o1.y = (selmask& 32u) ? e[5]*inv : 0.f;
  o1.z = (selmask& 64u) ? e[6]*inv : 0.f;
  o1.w = (selmask&128u) ? e[7]*inv : 0.f;
  float* outp = H + (size_t)row*512 + lane*8;
  *(float4*)outp     = o0;
  *(float4*)(outp+4) = o1;
}

// ============================================================================
extern "C" void kernel_launch(void* const* d_in, const int* in_sizes, int n_in,
                              void* d_out, int out_size, void* d_ws, size_t ws_size,
                              hipStream_t stream)
{
  const float* inputs = (const float*)d_in[0];
  const float* noise  = (const float*)d_in[1];
  const float* emu    = (const float*)d_in[2];
  const float* elsig  = (const float*)d_in[3];
  const float* Wq = (const float*)d_in[4];  const float* bq = (const float*)d_in[5];
  const float* Wk = (const float*)d_in[6];  const float* bk = (const float*)d_in[7];
  const float* Wv = (const float*)d_in[8];  const float* bv = (const float*)d_in[9];
  const float* W1 = (const float*)d_in[10]; const float* b1 = (const float*)d_in[11];
  const float* W2 = (const float*)d_in[12]; const float* b2 = (const float*)d_in[13];
  const float* g_in = (const float*)d_in[14]; const float* b_in = (const float*)d_in[15];
  const float* g_e  = (const float*)d_in[16]; const float* b_e  = (const float*)d_in[17];
  const int* knp = (const int*)d_in[18];
  const int* kep = (const int*)d_in[19];

  float* out = (float*)d_out;
  float* out_edges = out;                             // 512*1024
  float* out_H     = out + 512*1024;                  // 8192*512
  float* out_dots  = out + 512*1024 + 8192*512;       // 512*8192

  // ---- workspace (~112 MB peak, stream-ordered reuse) ----
  char* p = (char*)d_ws;
  const size_t MB = 1024ull*1024;
  u16* xh = (u16*)(p + 0*MB);            // x split, live to the end (dots_v)
  u16* xl = (u16*)(p + 16*MB);
  u16* kb = (u16*)(p + 32*MB);           // k bf16, dead after dots GEMM
  u16* vb = (u16*)(p + 48*MB);           // v bf16, dead after gather
  float* dotsvf = (float*)(p + 32*MB);   // dots_v fp32 (reuses kb region)
  // weights [64,88)
  u16* WkvTh = (u16*)(p + 64*MB);        // stacked [WkT;WvT], 2048x1024 (4MB)
  u16* WkTl  = (u16*)(p + 68*MB);
  u16* WqTh  = (u16*)(p + 70*MB);
  u16* Wqh   = (u16*)(p + 72*MB);  u16* Wql  = (u16*)(p + 74*MB);   // raw (no T)
  u16* W1Th  = (u16*)(p + 76*MB);  u16* W1Tl = (u16*)(p + 80*MB);
  u16* W2Th  = (u16*)(p + 84*MB);  u16* W2Tl = (u16*)(p + 86*MB);
  // small [88,102)
  u16* cath = (u16*)(p + 88*MB);  u16* catl = (u16*)(p + 90*MB);
  u16* qmb  = (u16*)(p + 92*MB);
  u16* h1h  = (u16*)(p + 93*MB);  u16* h1l  = (u16*)(p + 94*MB);
  u16* eoh  = (u16*)(p + 95*MB);  u16* eol  = (u16*)(p + 96*MB);
  u16* k2h  = (u16*)(p + 97*MB);  u16* k2l  = (u16*)(p + 98*MB);
  u16* Gth  = (u16*)(p + 99*MB);  u16* Gtl  = (u16*)(p + 100*MB);
  int*   tidx  = (int*)  (p + 101*MB);
  float* tw    = (float*)(p + 101*MB + 256*1024);
  float* biasv = (float*)(p + 101*MB + 512*1024);
  float* part  = (float*)(p + 104*MB);   // split-K partials: 4*512*1024*4 = 8MB

  hipMemsetAsync(tidx, 0, 512ull*128*4*2, stream);   // tidx + tw (contiguous)

  // fused weight prep (was 6 launches)
  prep_weights<<<7168,256,0,stream>>>(Wk, W1, W2, Wv, Wq,
                                      WkvTh, WkTl, W1Th, W1Tl, W2Th, W2Tl,
                                      WqTh, Wqh, Wql);
  // fused layernorms (was 2 launches)
  ln_all<<<8704,256,0,stream>>>(inputs, g_in, b_in, xh, xl,
                                noise, emu, elsig, g_e, b_e, cath, catl);

  const size_t MN = 512ull*1024;
  // --- dots chain (plain bf16; selection-tolerant) ---
  // k|v = relu(x@{Wk,Wv}+b): ONE launch, B stacked 2048 rows, grid (16,64)
  gemm_kv_128<<<dim3(16,64),256,0,stream>>>(xh,1024, WkvTh,1024, bk, bv,
                                            kb, vb, 1024);
  // qm = relu(cat@Wq+bq): M=512 -> 64-tile split-K4, grid (8,8,4)
  gemm1_64<false,4><<<dim3(8,8,4),256,0,stream>>>(cath,2048, WqTh,1024, nullptr, 1.f,
                                                  nullptr,nullptr, part, 1024,1024,512);
  reduce_epi<true,4><<<512,256,0,stream>>>(part, bq, 1.f, nullptr,nullptr, qmb,nullptr,
                                           MN, 1024, nullptr, nullptr);
  // dots = qm@k^T / 32 -> fp32 d_out: grid (8192/128, 512/128)
  gemm1_128<false><<<dim3(64,4),256,0,stream>>>(qmb,1024, kb,1024, nullptr, 0.03125f,
                                                nullptr,out_dots, 1024,8192);
  softmax_topk_a<<<512,256,0,stream>>>(out_dots, knp, tidx, tw);
  gather_updates<<<512,256,0,stream>>>(tidx, tw, knp, vb, cath, catl);

  // --- edges + H chain (split-bf16, fp32-class), all M=512 -> split-K4 ---
  gemm3_64<false,4><<<dim3(8,8,4),256,0,stream>>>(cath,catl,2048, W1Th,W1Tl,2048,
                                                  nullptr,1.f, nullptr,nullptr,nullptr,
                                                  part, 2048,1024,512);
  reduce_epi<true,4><<<512,256,0,stream>>>(part, b1, 1.f, h1h,h1l, nullptr,nullptr,
                                           MN, 1024, nullptr, nullptr);
  gemm3_64<false,4><<<dim3(8,8,4),256,0,stream>>>(h1h,h1l,1024, W2Th,W2Tl,1024,
                                                  nullptr,1.f, nullptr,nullptr,nullptr,
                                                  part, 1024,1024,512);
  reduce_epi<false,4><<<512,256,0,stream>>>(part, b2, 1.f, eoh,eol, nullptr,out_edges,
                                            MN, 1024, nullptr, nullptr);
  // k2 = relu(edges@Wk+bk); fused bias_v = dot(bq,k2_row)/32 per row
  gemm3_64<false,4><<<dim3(8,8,4),256,0,stream>>>(eoh,eol,1024, WkvTh,WkTl,1024,
                                                  nullptr,1.f, nullptr,nullptr,nullptr,
                                                  part, 1024,1024,512);
  reduce_epi<true,4><<<512,256,0,stream>>>(part, bk, 1.f, k2h,k2l, nullptr,nullptr,
                                           MN, 1024, bq, biasv);
  // Gt[m,e] = sum_d k2[m,d]*Wq[e,d]
  gemm3_64<false,4><<<dim3(8,8,4),256,0,stream>>>(k2h,k2l,1024, Wqh,Wql,1024,
                                                  nullptr,1.f, nullptr,nullptr,nullptr,
                                                  part, 1024,1024,512);
  reduce_epi<false,4><<<512,256,0,stream>>>(part, nullptr, 1.f, Gth,Gtl, nullptr,nullptr,
                                            MN, 1024, nullptr, nullptr);
  // dots_v = x@Gt^T / 32 + biasv : 128-tile, grid (512/128, 8192/128)
  gemm3_128<<<dim3(4,64),256,0,stream>>>(xh,xl,1024, Gth,Gtl,1024,
                                         biasv, 0.03125f, dotsvf, 1024,512);
  softmax_topk_h_wave<<<2048,256,0,stream>>>(dotsvf, kep, out_H);
}

// Round 9
// 417.875 us; speedup vs baseline: 1.0214x; 1.0214x over previous
//
#include <hip/hip_runtime.h>
#include <stdint.h>
#include <stddef.h>

typedef unsigned short u16;
typedef uint32_t u32;
typedef __bf16 bf16x8 __attribute__((ext_vector_type(8)));
typedef float f32x4 __attribute__((ext_vector_type(4)));

#define DEV __device__ __forceinline__

// Async global->LDS, 16B per lane. HW writes wave-uniform-base + lane*16;
// staging dests are &X[buf][tid*8] (u16) = base + lane*16B (linear). Counted
// in vmcnt; __syncthreads at END of iteration drains the PREFETCH issued at
// the TOP of the iteration -> load latency hides under the MFMA phase.
#define GLD16(g, l) __builtin_amdgcn_global_load_lds( \
    (const __attribute__((address_space(1))) u32*)(g), \
    (__attribute__((address_space(3))) u32*)(l), 16, 0, 0)

DEV float bf2f(u16 u){ union{uint32_t i; float f;} c; c.i=(uint32_t)u<<16; return c.f; }
DEV u16 f2bf(float f){ union{float f; uint32_t i;} c; c.f=f; uint32_t x=c.i;
  uint32_t r = x + 0x7FFFu + ((x>>16)&1u); return (u16)(r>>16); }
DEV uint32_t fmap(float f){ union{float f; uint32_t u;} c; c.f=f;
  return (c.u & 0x80000000u) ? ~c.u : (c.u | 0x80000000u); }
DEV float funmap(uint32_t u){ union{uint32_t u; float f;} c;
  c.u = (u & 0x80000000u) ? (u & 0x7FFFFFFFu) : ~u; return c.f; }
DEV void split2(float x, u16& h, u16& l){ h = f2bf(x); l = f2bf(x - bf2f(h)); }

// ---- block reductions (256 threads = 4 waves) ----
DEV float bredsum(float v, float* buf, int tid){
  #pragma unroll
  for(int o=32;o;o>>=1) v += __shfl_down(v,o);
  __syncthreads();
  if((tid&63)==0) buf[tid>>6]=v;
  __syncthreads();
  return buf[0]+buf[1]+buf[2]+buf[3];
}
DEV float bredmax(float v, float* buf, int tid){
  #pragma unroll
  for(int o=32;o;o>>=1) v = fmaxf(v, __shfl_down(v,o));
  __syncthreads();
  if((tid&63)==0) buf[tid>>6]=v;
  __syncthreads();
  return fmaxf(fmaxf(buf[0],buf[1]),fmaxf(buf[2],buf[3]));
}
DEV int bredsumi(int v, int* buf, int tid){
  #pragma unroll
  for(int o=32;o;o>>=1) v += __shfl_down(v,o);
  __syncthreads();
  if((tid&63)==0) buf[tid>>6]=v;
  __syncthreads();
  return buf[0]+buf[1]+buf[2]+buf[3];
}

// ============================================================================
// 64x128-tile plain bf16 GEMM (small-M split-K). GLD16 + LDS double-buffer.
// ============================================================================
template<bool RELU, int SK>
__global__ __launch_bounds__(256)
void gemm1_64(const u16* __restrict__ A, int lda,
              const u16* __restrict__ Bt, int ldb,
              const float* __restrict__ bias, float scale,
              u16* __restrict__ outb, float* __restrict__ outf,
              float* __restrict__ part,
              int K, int ldc, int M)
{
  __shared__ __align__(16) u16 As[2][64*32];
  __shared__ __align__(16) u16 Bs[2][128*32];
  const int tid = threadIdx.x, lane = tid&63, wave = tid>>6;
  const int m0 = blockIdx.y*64, n0 = blockIdx.x*128;
  const int wm = (wave>>1)*32, wn = (wave&1)*64;
  const int ml = lane&15, quad = lane>>4;
  const int ks = K / SK;
  const int kbeg = blockIdx.z * ks;
  const u16* pa  = A  + (size_t)(m0+(tid>>2))*lda + kbeg + (tid&3)*8;
  const u16* pb0 = Bt + (size_t)(n0+(tid>>2))*ldb + kbeg + (tid&3)*8;
  const u16* pb1 = Bt + (size_t)(n0+64+(tid>>2))*ldb + kbeg + (tid&3)*8;

  f32x4 acc[2][4];
  #pragma unroll
  for(int i=0;i<2;i++)
    #pragma unroll
    for(int j=0;j<4;j++) acc[i][j] = (f32x4){0.f,0.f,0.f,0.f};

  GLD16(pa , &As[0][tid*8]);
  GLD16(pb0, &Bs[0][tid*8]);
  GLD16(pb1, &Bs[0][(256+tid)*8]);
  __syncthreads();                       // drain tile0
  int cur = 0;
  for(int k0=0;k0<ks;k0+=32){
    const int nxt = cur^1;
    if(k0+32<ks){                        // prefetch t+1 into other buffer
      GLD16(pa +k0+32, &As[nxt][tid*8]);
      GLD16(pb0+k0+32, &Bs[nxt][tid*8]);
      GLD16(pb1+k0+32, &Bs[nxt][(256+tid)*8]);
    }
    bf16x8 af[2], bf[4];
    #pragma unroll
    for(int mi=0;mi<2;mi++) af[mi] = *(const bf16x8*)&As[cur][(wm+mi*16+ml)*32 + quad*8];
    #pragma unroll
    for(int ni=0;ni<4;ni++) bf[ni] = *(const bf16x8*)&Bs[cur][(wn+ni*16+ml)*32 + quad*8];
    #pragma unroll
    for(int mi=0;mi<2;mi++)
      #pragma unroll
      for(int ni=0;ni<4;ni++)
        acc[mi][ni] = __builtin_amdgcn_mfma_f32_16x16x32_bf16(af[mi], bf[ni], acc[mi][ni], 0,0,0);
    __syncthreads();                     // drain prefetch + guard reuse
    cur = nxt;
  }
  // C/D: col = lane&15, row = quad*4 + reg  (m89-verified)
  #pragma unroll
  for(int mi=0;mi<2;mi++){
    const int rbase = m0 + wm + mi*16 + quad*4;
    #pragma unroll
    for(int ni=0;ni<4;ni++){
      const int col = n0 + wn + ni*16 + ml;
      if(SK==1){
        const float bv = bias ? bias[col] : 0.f;
        #pragma unroll
        for(int r=0;r<4;r++){
          float v = acc[mi][ni][r]*scale + bv;
          if(RELU) v = fmaxf(v, 0.f);
          const size_t idx = (size_t)(rbase + r)*ldc + col;
          if(outb) outb[idx] = f2bf(v);
          if(outf) outf[idx] = v;
        }
      }else{
        #pragma unroll
        for(int r=0;r<4;r++)
          part[((size_t)blockIdx.z*M + rbase + r)*ldc + col] = acc[mi][ni][r];
      }
    }
  }
}

// ============================================================================
// 128x128-tile plain bf16 GEMM. GLD16 + LDS double-buffer.
// ============================================================================
template<bool RELU>
__global__ __launch_bounds__(256)
void gemm1_128(const u16* __restrict__ A, int lda,
               const u16* __restrict__ Bt, int ldb,
               const float* __restrict__ bias, float scale,
               u16* __restrict__ outb, float* __restrict__ outf,
               int K, int ldc)
{
  __shared__ __align__(16) u16 As[2][128*32];
  __shared__ __align__(16) u16 Bs[2][128*32];
  const int tid = threadIdx.x, lane = tid&63, wave = tid>>6;
  const int m0 = blockIdx.y*128, n0 = blockIdx.x*128;
  const int wm = (wave>>1)*64, wn = (wave&1)*64;
  const int ml = lane&15, quad = lane>>4;
  const u16* pa0 = A  + (size_t)(m0+(tid>>2))*lda    + (tid&3)*8;
  const u16* pa1 = A  + (size_t)(m0+64+(tid>>2))*lda + (tid&3)*8;
  const u16* pb0 = Bt + (size_t)(n0+(tid>>2))*ldb    + (tid&3)*8;
  const u16* pb1 = Bt + (size_t)(n0+64+(tid>>2))*ldb + (tid&3)*8;

  f32x4 acc[4][4];
  #pragma unroll
  for(int i=0;i<4;i++)
    #pragma unroll
    for(int j=0;j<4;j++) acc[i][j] = (f32x4){0.f,0.f,0.f,0.f};

  GLD16(pa0, &As[0][tid*8]);
  GLD16(pa1, &As[0][(256+tid)*8]);
  GLD16(pb0, &Bs[0][tid*8]);
  GLD16(pb1, &Bs[0][(256+tid)*8]);
  __syncthreads();
  int cur = 0;
  for(int k0=0;k0<K;k0+=32){
    const int nxt = cur^1;
    if(k0+32<K){
      GLD16(pa0+k0+32, &As[nxt][tid*8]);
      GLD16(pa1+k0+32, &As[nxt][(256+tid)*8]);
      GLD16(pb0+k0+32, &Bs[nxt][tid*8]);
      GLD16(pb1+k0+32, &Bs[nxt][(256+tid)*8]);
    }
    bf16x8 af[4], bf[4];
    #pragma unroll
    for(int mi=0;mi<4;mi++) af[mi] = *(const bf16x8*)&As[cur][(wm+mi*16+ml)*32 + quad*8];
    #pragma unroll
    for(int ni=0;ni<4;ni++) bf[ni] = *(const bf16x8*)&Bs[cur][(wn+ni*16+ml)*32 + quad*8];
    #pragma unroll
    for(int mi=0;mi<4;mi++)
      #pragma unroll
      for(int ni=0;ni<4;ni++)
        acc[mi][ni] = __builtin_amdgcn_mfma_f32_16x16x32_bf16(af[mi], bf[ni], acc[mi][ni], 0,0,0);
    __syncthreads();
    cur = nxt;
  }
  #pragma unroll
  for(int mi=0;mi<4;mi++){
    const int rbase = m0 + wm + mi*16 + quad*4;
    #pragma unroll
    for(int ni=0;ni<4;ni++){
      const int col = n0 + wn + ni*16 + ml;
      const float bv = bias ? bias[col] : 0.f;
      #pragma unroll
      for(int r=0;r<4;r++){
        float v = acc[mi][ni][r]*scale + bv;
        if(RELU) v = fmaxf(v, 0.f);
        const size_t idx = (size_t)(rbase + r)*ldc + col;
        if(outb) outb[idx] = f2bf(v);
        if(outf) outf[idx] = v;
      }
    }
  }
}

// ============================================================================
// Fused k|v GEMM: B = [WkT ; WvT] stacked (2048 rows). GLD16 + double-buffer.
// ============================================================================
__global__ __launch_bounds__(256)
void gemm_kv_128(const u16* __restrict__ A, int lda,
                 const u16* __restrict__ Bt, int ldb,
                 const float* __restrict__ bk, const float* __restrict__ bv,
                 u16* __restrict__ kb, u16* __restrict__ vb, int K)
{
  __shared__ __align__(16) u16 As[2][128*32];
  __shared__ __align__(16) u16 Bs[2][128*32];
  const int tid = threadIdx.x, lane = tid&63, wave = tid>>6;
  const int m0 = blockIdx.y*128, n0 = blockIdx.x*128;
  const int wm = (wave>>1)*64, wn = (wave&1)*64;
  const int ml = lane&15, quad = lane>>4;
  const u16* pa0 = A  + (size_t)(m0+(tid>>2))*lda    + (tid&3)*8;
  const u16* pa1 = A  + (size_t)(m0+64+(tid>>2))*lda + (tid&3)*8;
  const u16* pb0 = Bt + (size_t)(n0+(tid>>2))*ldb    + (tid&3)*8;
  const u16* pb1 = Bt + (size_t)(n0+64+(tid>>2))*ldb + (tid&3)*8;

  f32x4 acc[4][4];
  #pragma unroll
  for(int i=0;i<4;i++)
    #pragma unroll
    for(int j=0;j<4;j++) acc[i][j] = (f32x4){0.f,0.f,0.f,0.f};

  GLD16(pa0, &As[0][tid*8]);
  GLD16(pa1, &As[0][(256+tid)*8]);
  GLD16(pb0, &Bs[0][tid*8]);
  GLD16(pb1, &Bs[0][(256+tid)*8]);
  __syncthreads();
  int cur = 0;
  for(int k0=0;k0<K;k0+=32){
    const int nxt = cur^1;
    if(k0+32<K){
      GLD16(pa0+k0+32, &As[nxt][tid*8]);
      GLD16(pa1+k0+32, &As[nxt][(256+tid)*8]);
      GLD16(pb0+k0+32, &Bs[nxt][tid*8]);
      GLD16(pb1+k0+32, &Bs[nxt][(256+tid)*8]);
    }
    bf16x8 af[4], bf[4];
    #pragma unroll
    for(int mi=0;mi<4;mi++) af[mi] = *(const bf16x8*)&As[cur][(wm+mi*16+ml)*32 + quad*8];
    #pragma unroll
    for(int ni=0;ni<4;ni++) bf[ni] = *(const bf16x8*)&Bs[cur][(wn+ni*16+ml)*32 + quad*8];
    #pragma unroll
    for(int mi=0;mi<4;mi++)
      #pragma unroll
      for(int ni=0;ni<4;ni++)
        acc[mi][ni] = __builtin_amdgcn_mfma_f32_16x16x32_bf16(af[mi], bf[ni], acc[mi][ni], 0,0,0);
    __syncthreads();
    cur = nxt;
  }
  #pragma unroll
  for(int mi=0;mi<4;mi++){
    const int rbase = m0 + wm + mi*16 + quad*4;
    #pragma unroll
    for(int ni=0;ni<4;ni++){
      const int col = n0 + wn + ni*16 + ml;      // 0..2047
      const bool isv = col >= 1024;
      const int c2 = col & 1023;
      const float bb = isv ? bv[c2] : bk[c2];
      u16* outp = isv ? vb : kb;
      #pragma unroll
      for(int r=0;r<4;r++){
        const float v = fmaxf(acc[mi][ni][r] + bb, 0.f);
        outp[(size_t)(rbase + r)*1024 + c2] = f2bf(v);
      }
    }
  }
}

// ============================================================================
// 64x128-tile split-bf16 GEMM (small-M split-K). GLD16 + double-buffer.
// ============================================================================
template<bool RELU, int SK>
__global__ __launch_bounds__(256)
void gemm3_64(const u16* __restrict__ Ah, const u16* __restrict__ Al, int lda,
              const u16* __restrict__ Bh, const u16* __restrict__ Bl, int ldb,
              const float* __restrict__ bias, float scale,
              u16* __restrict__ outh, u16* __restrict__ outl,
              float* __restrict__ outf, float* __restrict__ part,
              int K, int ldc, int M)
{
  __shared__ __align__(16) u16 AsH[2][64*32];
  __shared__ __align__(16) u16 AsL[2][64*32];
  __shared__ __align__(16) u16 BsH[2][128*32];
  __shared__ __align__(16) u16 BsL[2][128*32];
  const int tid = threadIdx.x, lane = tid&63, wave = tid>>6;
  const int m0 = blockIdx.y*64, n0 = blockIdx.x*128;
  const int wm = (wave>>1)*32, wn = (wave&1)*64;
  const int ml = lane&15, quad = lane>>4;
  const int ks = K / SK;
  const int kbeg = blockIdx.z * ks;
  const u16* pah  = Ah + (size_t)(m0+(tid>>2))*lda + kbeg + (tid&3)*8;
  const u16* pal  = Al + (size_t)(m0+(tid>>2))*lda + kbeg + (tid&3)*8;
  const u16* pbh0 = Bh + (size_t)(n0+(tid>>2))*ldb + kbeg + (tid&3)*8;
  const u16* pbl0 = Bl + (size_t)(n0+(tid>>2))*ldb + kbeg + (tid&3)*8;
  const u16* pbh1 = Bh + (size_t)(n0+64+(tid>>2))*ldb + kbeg + (tid&3)*8;
  const u16* pbl1 = Bl + (size_t)(n0+64+(tid>>2))*ldb + kbeg + (tid&3)*8;

  f32x4 acc[2][4];
  #pragma unroll
  for(int i=0;i<2;i++)
    #pragma unroll
    for(int j=0;j<4;j++) acc[i][j] = (f32x4){0.f,0.f,0.f,0.f};

  GLD16(pah , &AsH[0][tid*8]);
  GLD16(pal , &AsL[0][tid*8]);
  GLD16(pbh0, &BsH[0][tid*8]);
  GLD16(pbl0, &BsL[0][tid*8]);
  GLD16(pbh1, &BsH[0][(256+tid)*8]);
  GLD16(pbl1, &BsL[0][(256+tid)*8]);
  __syncthreads();
  int cur = 0;
  for(int k0=0;k0<ks;k0+=32){
    const int nxt = cur^1;
    if(k0+32<ks){
      GLD16(pah +k0+32, &AsH[nxt][tid*8]);
      GLD16(pal +k0+32, &AsL[nxt][tid*8]);
      GLD16(pbh0+k0+32, &BsH[nxt][tid*8]);
      GLD16(pbl0+k0+32, &BsL[nxt][tid*8]);
      GLD16(pbh1+k0+32, &BsH[nxt][(256+tid)*8]);
      GLD16(pbl1+k0+32, &BsL[nxt][(256+tid)*8]);
    }
    bf16x8 afh[2], afl[2], bfh[4], bfl[4];
    #pragma unroll
    for(int mi=0;mi<2;mi++){
      const int o = (wm+mi*16+ml)*32 + quad*8;
      afh[mi] = *(const bf16x8*)&AsH[cur][o];
      afl[mi] = *(const bf16x8*)&AsL[cur][o];
    }
    #pragma unroll
    for(int ni=0;ni<4;ni++){
      const int o = (wn+ni*16+ml)*32 + quad*8;
      bfh[ni] = *(const bf16x8*)&BsH[cur][o];
      bfl[ni] = *(const bf16x8*)&BsL[cur][o];
    }
    #pragma unroll
    for(int mi=0;mi<2;mi++)
      #pragma unroll
      for(int ni=0;ni<4;ni++){
        acc[mi][ni] = __builtin_amdgcn_mfma_f32_16x16x32_bf16(afh[mi], bfh[ni], acc[mi][ni], 0,0,0);
        acc[mi][ni] = __builtin_amdgcn_mfma_f32_16x16x32_bf16(afh[mi], bfl[ni], acc[mi][ni], 0,0,0);
        acc[mi][ni] = __builtin_amdgcn_mfma_f32_16x16x32_bf16(afl[mi], bfh[ni], acc[mi][ni], 0,0,0);
      }
    __syncthreads();
    cur = nxt;
  }
  #pragma unroll
  for(int mi=0;mi<2;mi++){
    const int rbase = m0 + wm + mi*16 + quad*4;
    #pragma unroll
    for(int ni=0;ni<4;ni++){
      const int col = n0 + wn + ni*16 + ml;
      if(SK==1){
        const float bv = bias ? bias[col] : 0.f;
        #pragma unroll
        for(int r=0;r<4;r++){
          float v = acc[mi][ni][r]*scale + bv;
          if(RELU) v = fmaxf(v, 0.f);
          const size_t idx = (size_t)(rbase + r)*ldc + col;
          if(outh){ u16 h, l; split2(v, h, l); outh[idx] = h; outl[idx] = l; }
          if(outf) outf[idx] = v;
        }
      }else{
        #pragma unroll
        for(int r=0;r<4;r++)
          part[((size_t)blockIdx.z*M + rbase + r)*ldc + col] = acc[mi][ni][r];
      }
    }
  }
}

// ============================================================================
// 128x128-tile split-bf16 GEMM (fp32-class). GLD16 + double-buffer (64KB LDS;
// grid is 1 block/CU so the occupancy cap is irrelevant).
// ============================================================================
__global__ __launch_bounds__(256)
void gemm3_128(const u16* __restrict__ Ah, const u16* __restrict__ Al, int lda,
               const u16* __restrict__ Bh, const u16* __restrict__ Bl, int ldb,
               const float* __restrict__ bias, float scale,
               float* __restrict__ outf, int K, int ldc)
{
  __shared__ __align__(16) u16 AsH[2][128*32];
  __shared__ __align__(16) u16 AsL[2][128*32];
  __shared__ __align__(16) u16 BsH[2][128*32];
  __shared__ __align__(16) u16 BsL[2][128*32];
  const int tid = threadIdx.x, lane = tid&63, wave = tid>>6;
  const int m0 = blockIdx.y*128, n0 = blockIdx.x*128;
  const int wm = (wave>>1)*64, wn = (wave&1)*64;
  const int ml = lane&15, quad = lane>>4;
  const u16* pah0 = Ah + (size_t)(m0+(tid>>2))*lda    + (tid&3)*8;
  const u16* pah1 = Ah + (size_t)(m0+64+(tid>>2))*lda + (tid&3)*8;
  const u16* pal0 = Al + (size_t)(m0+(tid>>2))*lda    + (tid&3)*8;
  const u16* pal1 = Al + (size_t)(m0+64+(tid>>2))*lda + (tid&3)*8;
  const u16* pbh0 = Bh + (size_t)(n0+(tid>>2))*ldb    + (tid&3)*8;
  const u16* pbh1 = Bh + (size_t)(n0+64+(tid>>2))*ldb + (tid&3)*8;
  const u16* pbl0 = Bl + (size_t)(n0+(tid>>2))*ldb    + (tid&3)*8;
  const u16* pbl1 = Bl + (size_t)(n0+64+(tid>>2))*ldb + (tid&3)*8;

  f32x4 acc[4][4];
  #pragma unroll
  for(int i=0;i<4;i++)
    #pragma unroll
    for(int j=0;j<4;j++) acc[i][j] = (f32x4){0.f,0.f,0.f,0.f};

  GLD16(pah0, &AsH[0][tid*8]);
  GLD16(pah1, &AsH[0][(256+tid)*8]);
  GLD16(pal0, &AsL[0][tid*8]);
  GLD16(pal1, &AsL[0][(256+tid)*8]);
  GLD16(pbh0, &BsH[0][tid*8]);
  GLD16(pbh1, &BsH[0][(256+tid)*8]);
  GLD16(pbl0, &BsL[0][tid*8]);
  GLD16(pbl1, &BsL[0][(256+tid)*8]);
  __syncthreads();
  int cur = 0;
  for(int k0=0;k0<K;k0+=32){
    const int nxt = cur^1;
    if(k0+32<K){
      GLD16(pah0+k0+32, &AsH[nxt][tid*8]);
      GLD16(pah1+k0+32, &AsH[nxt][(256+tid)*8]);
      GLD16(pal0+k0+32, &AsL[nxt][tid*8]);
      GLD16(pal1+k0+32, &AsL[nxt][(256+tid)*8]);
      GLD16(pbh0+k0+32, &BsH[nxt][tid*8]);
      GLD16(pbh1+k0+32, &BsH[nxt][(256+tid)*8]);
      GLD16(pbl0+k0+32, &BsL[nxt][tid*8]);
      GLD16(pbl1+k0+32, &BsL[nxt][(256+tid)*8]);
    }
    bf16x8 afh[4], afl[4], bfh[4], bfl[4];
    #pragma unroll
    for(int mi=0;mi<4;mi++){
      const int o = (wm+mi*16+ml)*32 + quad*8;
      afh[mi] = *(const bf16x8*)&AsH[cur][o];
      afl[mi] = *(const bf16x8*)&AsL[cur][o];
    }
    #pragma unroll
    for(int ni=0;ni<4;ni++){
      const int o = (wn+ni*16+ml)*32 + quad*8;
      bfh[ni] = *(const bf16x8*)&BsH[cur][o];
      bfl[ni] = *(const bf16x8*)&BsL[cur][o];
    }
    #pragma unroll
    for(int mi=0;mi<4;mi++)
      #pragma unroll
      for(int ni=0;ni<4;ni++){
        acc[mi][ni] = __builtin_amdgcn_mfma_f32_16x16x32_bf16(afh[mi], bfh[ni], acc[mi][ni], 0,0,0);
        acc[mi][ni] = __builtin_amdgcn_mfma_f32_16x16x32_bf16(afh[mi], bfl[ni], acc[mi][ni], 0,0,0);
        acc[mi][ni] = __builtin_amdgcn_mfma_f32_16x16x32_bf16(afl[mi], bfh[ni], acc[mi][ni], 0,0,0);
      }
    __syncthreads();
    cur = nxt;
  }
  #pragma unroll
  for(int mi=0;mi<4;mi++){
    const int rbase = m0 + wm + mi*16 + quad*4;
    #pragma unroll
    for(int ni=0;ni<4;ni++){
      const int col = n0 + wn + ni*16 + ml;
      const float bv = bias ? bias[col] : 0.f;
      #pragma unroll
      for(int r=0;r<4;r++){
        const float v = acc[mi][ni][r]*scale + bv;
        outf[(size_t)(rbase + r)*ldc + col] = v;
      }
    }
  }
}

// ============================================================================
// reduce SK fp32 partials + bias/act -> split-bf16 / bf16 / fp32 outputs.
// Optional fused row-dot: bvout[row] = dot(bqv, rowvals)/32 (block == 1 row).
// ============================================================================
template<bool RELU, int SK>
__global__ __launch_bounds__(256)
void reduce_epi(const float* __restrict__ part, const float* __restrict__ bias,
                float scale, u16* __restrict__ outh, u16* __restrict__ outl,
                u16* __restrict__ outb, float* __restrict__ outf,
                size_t MN, int N,
                const float* __restrict__ bqv, float* __restrict__ bvout)
{
  __shared__ float buf[4];
  const int tid = threadIdx.x;
  const size_t i = ((size_t)blockIdx.x*256 + tid)*4;
  float4 s = *(const float4*)(part + i);
  #pragma unroll
  for(int z=1; z<SK; z++){
    const float4 t = *(const float4*)(part + (size_t)z*MN + i);
    s.x += t.x; s.y += t.y; s.z += t.z; s.w += t.w;
  }
  const int col = (int)(i % (size_t)N);
  float4 bv = bias ? *(const float4*)(bias + col) : (float4){0.f,0.f,0.f,0.f};
  float v[4] = { s.x*scale + bv.x, s.y*scale + bv.y, s.z*scale + bv.z, s.w*scale + bv.w };
  if(RELU){
    #pragma unroll
    for(int j=0;j<4;j++) v[j] = fmaxf(v[j], 0.f);
  }
  if(outh){
    ushort4 h4, l4;
    split2(v[0], h4.x, l4.x); split2(v[1], h4.y, l4.y);
    split2(v[2], h4.z, l4.z); split2(v[3], h4.w, l4.w);
    *(ushort4*)(outh + i) = h4;
    *(ushort4*)(outl + i) = l4;
  }
  if(outb){
    ushort4 b4;
    b4.x=f2bf(v[0]); b4.y=f2bf(v[1]); b4.z=f2bf(v[2]); b4.w=f2bf(v[3]);
    *(ushort4*)(outb + i) = b4;
  }
  if(outf) *(float4*)(outf + i) = (float4){v[0],v[1],v[2],v[3]};
  if(bvout){   // uniform branch; block == one row (N==1024, 256 thr x 4)
    const float4 q = *(const float4*)(bqv + col);
    float d = q.x*v[0] + q.y*v[1] + q.z*v[2] + q.w*v[3];
    d = bredsum(d, buf, tid);
    if(tid==0) bvout[blockIdx.x] = d * 0.03125f;
  }
}

// ============================================================================
// Fused weight prep: all transposes + split conversions in ONE launch.
// ============================================================================
DEV void dev_tsplit(const float* in, u16* oh, u16* ol, int R, int C,
                    int bx, int by, int tid, float (*tile)[33])
{
  const int tx = tid & 31, ty = tid >> 5;
  #pragma unroll
  for(int i=0;i<32;i+=8)
    tile[ty+i][tx] = in[(size_t)(by*32+ty+i)*C + bx*32 + tx];
  __syncthreads();
  #pragma unroll
  for(int i=0;i<32;i+=8){
    const float v = tile[tx][ty+i];
    u16 h, l; split2(v, h, l);
    const size_t o = (size_t)(bx*32+ty+i)*R + by*32 + tx;
    oh[o] = h; if(ol) ol[o] = l;
  }
}
__global__ __launch_bounds__(256)
void prep_weights(const float* __restrict__ Wk, const float* __restrict__ W1,
                  const float* __restrict__ W2, const float* __restrict__ Wv,
                  const float* __restrict__ Wq,
                  u16* __restrict__ WkvTh, u16* __restrict__ WkTl,
                  u16* __restrict__ W1Th,  u16* __restrict__ W1Tl,
                  u16* __restrict__ W2Th,  u16* __restrict__ W2Tl,
                  u16* __restrict__ WqTh,
                  u16* __restrict__ Wqh,   u16* __restrict__ Wql)
{
  __shared__ float tile[32][33];
  const int id = blockIdx.x, tid = threadIdx.x;
  if(id < 1024){
    dev_tsplit(Wk, WkvTh, WkTl, 1024, 1024, id&31, id>>5, tid, tile);
  }else if(id < 3072){
    const int l = id - 1024;
    dev_tsplit(W1, W1Th, W1Tl, 2048, 1024, l&31, l>>5, tid, tile);
  }else if(id < 4096){
    const int l = id - 3072;
    dev_tsplit(W2, W2Th, W2Tl, 1024, 1024, l&31, l>>5, tid, tile);
  }else if(id < 5120){
    const int l = id - 4096;
    dev_tsplit(Wv, WkvTh + 1024*1024, nullptr, 1024, 1024, l&31, l>>5, tid, tile);
  }else if(id < 6144){
    const int l = id - 5120;
    dev_tsplit(Wq, WqTh, nullptr, 1024, 1024, l&31, l>>5, tid, tile);
  }else{
    const int l = id - 6144;
    const int i = l*256 + tid;
    const float4 v = ((const float4*)Wq)[i];
    ushort4 h4, l4;
    split2(v.x, h4.x, l4.x); split2(v.y, h4.y, l4.y);
    split2(v.z, h4.z, l4.z); split2(v.w, h4.w, l4.w);
    ((ushort4*)Wqh)[i] = h4; ((ushort4*)Wql)[i] = l4;
  }
}

// ============================================================================
// Fused LayerNorms: blocks [0,8192) = input rows -> xh/xl (stride 1024);
// blocks [8192,8704) = edge rows (mu + exp(lsig)*noise) -> cath/catl (2048).
// ============================================================================
__global__ __launch_bounds__(256)
void ln_all(const float* __restrict__ in, const float* __restrict__ g,
            const float* __restrict__ bb, u16* __restrict__ outh,
            u16* __restrict__ outl,
            const float* __restrict__ noise, const float* __restrict__ mu,
            const float* __restrict__ lsig, const float* __restrict__ ge,
            const float* __restrict__ be, u16* __restrict__ cath,
            u16* __restrict__ catl)
{
  __shared__ float buf[4];
  const int tid = threadIdx.x;
  const bool edge = blockIdx.x >= 8192;
  const int row = edge ? (blockIdx.x - 8192) : blockIdx.x;
  float v0,v1,v2,v3;
  if(!edge){
    const float4 xv = ((const float4*)(in + (size_t)row*1024))[tid];
    v0=xv.x; v1=xv.y; v2=xv.z; v3=xv.w;
  }else{
    const float4 nv  = ((const float4*)(noise + (size_t)row*1024))[tid];
    const float4 muv = ((const float4*)mu)[tid];
    const float4 lsv = ((const float4*)lsig)[tid];
    v0 = muv.x + expf(lsv.x)*nv.x;
    v1 = muv.y + expf(lsv.y)*nv.y;
    v2 = muv.z + expf(lsv.z)*nv.z;
    v3 = muv.w + expf(lsv.w)*nv.w;
  }
  float s  = bredsum(v0+v1+v2+v3, buf, tid);
  float s2 = bredsum(v0*v0+v1*v1+v2*v2+v3*v3, buf, tid);
  const float mean = s * (1.f/1024.f);
  const float var  = s2 * (1.f/1024.f) - mean*mean;
  const float rs   = 1.f / sqrtf(var + 1e-5f);
  const float4 gv = ((const float4*)(edge?ge:g))[tid];
  const float4 bv = ((const float4*)(edge?be:bb))[tid];
  float o0 = (v0-mean)*rs*gv.x + bv.x;
  float o1 = (v1-mean)*rs*gv.y + bv.y;
  float o2 = (v2-mean)*rs*gv.z + bv.z;
  float o3 = (v3-mean)*rs*gv.w + bv.w;
  ushort4 oh, ol;
  split2(o0, oh.x, ol.x); split2(o1, oh.y, ol.y);
  split2(o2, oh.z, ol.z); split2(o3, oh.w, ol.w);
  u16* ph = edge ? cath : outh;
  u16* pl = edge ? catl : outl;
  const int ostride = edge ? 2048 : 1024;
  ((ushort4*)(ph + (size_t)row*ostride))[tid] = oh;
  ((ushort4*)(pl + (size_t)row*ostride))[tid] = ol;
}

// ============================================================================
// softmax(8192)+eps+renorm + top-k_n -> (idx, weight) pairs. 1 block/row.
// ============================================================================
#define SWZ(i) ((i) ^ (((((unsigned)(i))>>5)&7u)<<2))
__global__ __launch_bounds__(256)
void softmax_topk_a(const float* __restrict__ dots, const int* __restrict__ knp,
                    int* __restrict__ tidx, float* __restrict__ tw)
{
  const int NC = 8192;
  __shared__ __align__(16) uint32_t us[8192];
  __shared__ float fbuf[4];
  __shared__ int ibuf[4];
  __shared__ int scan[256];
  __shared__ uint32_t hist[256];
  __shared__ uint32_t bcast;
  __shared__ int slot_ctr;
  const int row = blockIdx.x, tid = threadIdx.x;
  const int lane = tid & 63, wave = tid >> 6;
  const float* x = dots + (size_t)row * NC;

  float mx = -3.4e38f;
  #pragma unroll
  for(int it=0; it<8; ++it){
    const int i = (tid + it*256)*4;
    const float4 f = *(const float4*)(x + i);
    mx = fmaxf(fmaxf(mx, fmaxf(f.x,f.y)), fmaxf(f.z,f.w));
    uint4 u; u.x=fmap(f.x); u.y=fmap(f.y); u.z=fmap(f.z); u.w=fmap(f.w);
    *(uint4*)&us[SWZ(i)] = u;
  }
  mx = bredmax(mx, fbuf, tid);

  float se = 0.f;
  #pragma unroll
  for(int it=0; it<8; ++it){
    const int i = (tid + it*256)*4;
    const uint4 u = *(const uint4*)&us[SWZ(i)];
    se += expf(funmap(u.x)-mx) + expf(funmap(u.y)-mx)
        + expf(funmap(u.z)-mx) + expf(funmap(u.w)-mx);
  }
  se = bredsum(se, fbuf, tid);
  const float T = 1.f + (float)NC * 1e-8f;

  const int k = knp[0];
  const int base = tid*32;

  uint32_t prefix = 0;
  int remaining = k;
  #pragma unroll
  for(int shift=24; shift>=0; shift-=8){
    hist[tid] = 0;
    __syncthreads();
    const uint32_t himask = (shift==24) ? 0u : (0xFFFFFFFFu << (shift+8));
    #pragma unroll
    for(int j=0;j<32;j+=4){
      const uint4 u4 = *(const uint4*)&us[SWZ(base+j)];
      const uint32_t uu[4] = {u4.x,u4.y,u4.z,u4.w};
      #pragma unroll
      for(int t=0;t<4;t++)
        if((uu[t] & himask) == prefix) atomicAdd(&hist[(uu[t]>>shift)&255u], 1u);
    }
    __syncthreads();
    if(wave==0){
      const uint32_t h0=hist[4*lane], h1=hist[4*lane+1],
                     h2=hist[4*lane+2], h3=hist[4*lane+3];
      const uint32_t s3=h3, s2=h2+s3, s1=h1+s2, s0=h0+s1;
      uint32_t tsum = s0;
      #pragma unroll
      for(int o=1;o<64;o<<=1){
        const uint32_t vv = __shfl_down(tsum, o);
        if(lane + o < 64) tsum += vv;
      }
      const uint32_t excl = tsum - s0;
      const uint32_t r = (uint32_t)remaining;
      int cand = -1; uint32_t gsel = 0;
      if     (s3+excl >= r){ cand = 4*lane+3; gsel = excl; }
      else if(s2+excl >= r){ cand = 4*lane+2; gsel = s3+excl; }
      else if(s1+excl >= r){ cand = 4*lane+1; gsel = s2+excl; }
      else if(s0+excl >= r){ cand = 4*lane+0; gsel = s1+excl; }
      int bestc = cand; uint32_t bestg = gsel;
      #pragma unroll
      for(int o=32;o;o>>=1){
        const int oc = __shfl_xor(bestc, o);
        const uint32_t og = __shfl_xor(bestg, o);
        if(oc > bestc){ bestc = oc; bestg = og; }
      }
      if(lane==0) bcast = (uint32_t)bestc;
      remaining -= (int)bestg;
    }
    __syncthreads();
    prefix |= bcast << shift;
  }
  const uint32_t uth = prefix;

  int gt = 0, eq = 0;
  #pragma unroll
  for(int j=0;j<32;j+=4){
    const uint4 u4 = *(const uint4*)&us[SWZ(base+j)];
    gt += (u4.x>uth)+(u4.y>uth)+(u4.z>uth)+(u4.w>uth);
    eq += (u4.x==uth)+(u4.y==uth)+(u4.z==uth)+(u4.w==uth);
  }
  const int c1 = bredsumi(gt, ibuf, tid);
  __syncthreads();
  scan[tid] = eq;
  __syncthreads();
  #pragma unroll
  for(int o=1;o<256;o<<=1){
    int t = (tid>=o) ? scan[tid-o] : 0;
    __syncthreads();
    scan[tid] += t;
    __syncthreads();
  }
  int eq_rank = scan[tid] - eq;
  const int budget = k - c1;
  if(tid==0) slot_ctr = 0;
  __syncthreads();
  #pragma unroll 2
  for(int j=0;j<32;j+=4){
    const uint4 u4 = *(const uint4*)&us[SWZ(base+j)];
    const uint32_t uu[4] = {u4.x,u4.y,u4.z,u4.w};
    #pragma unroll
    for(int t=0;t<4;t++){
      const uint32_t u = uu[t];
      bool sel = (u > uth);
      if(u == uth){ sel = (eq_rank < budget); eq_rank++; }
      if(sel){
        const int s = atomicAdd(&slot_ctr, 1);
        const float f = funmap(u);
        const float w = (expf(f - mx)/se + 1e-8f) / T;
        if(s < 128){ tidx[row*128 + s] = base + j + t; tw[row*128 + s] = w; }
      }
    }
  }
}

// updates[row] = sum_j w_j * v[idx_j] (v bf16) ; split-bf16 into cat[:,1024:]
__global__ __launch_bounds__(256)
void gather_updates(const int* __restrict__ tidx, const float* __restrict__ tw,
                    const int* __restrict__ knp, const u16* __restrict__ v,
                    u16* __restrict__ cath, u16* __restrict__ catl)
{
  __shared__ int   idx_s[128];
  __shared__ float w_s[128];
  const int row = blockIdx.x, tid = threadIdx.x;
  const int kk = knp[0];
  if(tid < 128){
    idx_s[tid] = (tid < kk) ? (tidx[row*128+tid] & 8191) : 0;
    w_s[tid]   = (tid < kk) ? tw[row*128+tid] : 0.f;
  }
  __syncthreads();
  const int c = tid*4;
  float a0=0,a1=0,a2=0,a3=0;
  for(int j=0;j<kk && j<128;j++){
    const ushort4 vv = *(const ushort4*)&v[(size_t)idx_s[j]*1024 + c];
    const float w = w_s[j];
    a0 += w*bf2f(vv.x); a1 += w*bf2f(vv.y); a2 += w*bf2f(vv.z); a3 += w*bf2f(vv.w);
  }
  ushort4 oh, ol;
  split2(a0, oh.x, ol.x); split2(a1, oh.y, ol.y);
  split2(a2, oh.z, ol.z); split2(a3, oh.w, ol.w);
  ((ushort4*)(cath + (size_t)row*2048 + 1024))[tid] = oh;
  ((ushort4*)(catl + (size_t)row*2048 + 1024))[tid] = ol;
}

// ============================================================================
// H: softmax over 512 + top-k_e mask, one WAVE per row (4 rows/block).
// ============================================================================
__global__ __launch_bounds__(256)
void softmax_topk_h_wave(const float* __restrict__ dv, const int* __restrict__ kep,
                         float* __restrict__ H)
{
  const int wave = threadIdx.x >> 6, lane = threadIdx.x & 63;
  const int row = blockIdx.x*4 + wave;
  const float* x = dv + (size_t)row*512 + lane*8;
  const float4 a = *(const float4*)x;
  const float4 b = *(const float4*)(x+4);
  float vals[8] = {a.x,a.y,a.z,a.w,b.x,b.y,b.z,b.w};

  float mx = vals[0];
  #pragma unroll
  for(int j=1;j<8;j++) mx = fmaxf(mx, vals[j]);
  #pragma unroll
  for(int o=32;o;o>>=1) mx = fmaxf(mx, __shfl_xor(mx, o));
  float e[8], se = 0.f;
  #pragma unroll
  for(int j=0;j<8;j++){ e[j] = expf(vals[j]-mx); se += e[j]; }
  #pragma unroll
  for(int o=32;o;o>>=1) se += __shfl_xor(se, o);
  const float inv = 1.f/se;

  const int k = kep[0];
  unsigned int selmask = 0;
  for(int r=0;r<k;r++){
    unsigned long long best = 0;
    #pragma unroll
    for(int j=0;j<8;j++){
      if(!((selmask>>j)&1u)){
        const unsigned long long key =
          ((unsigned long long)fmap(vals[j]) << 9) | (unsigned long long)(511 - (lane*8+j));
        if(key > best) best = key;
      }
    }
    #pragma unroll
    for(int o=32;o;o>>=1){
      const unsigned long long other = __shfl_xor(best, o);
      if(other > best) best = other;
    }
    const int bidx = 511 - (int)(best & 511ull);
    if((bidx>>3) == lane) selmask |= 1u << (bidx & 7);
  }

  float4 o0, o1;
  o0.x = (selmask&  1u) ? e[0]*inv : 0.f;
  o0.y = (selmask&  2u) ? e[1]*inv : 0.f;
  o0.z = (selmask&  4u) ? e[2]*inv : 0.f;
  o0.w = (selmask&  8u) ? e[3]*inv : 0.f;
  o1.x = (selmask& 16u) ? e[4]*inv : 0.f;
  o1.y = (selmask& 32u) ? e[5]*inv : 0.f;
  o1.z = (selmask& 64u) ? e[6]*inv : 0.f;
  o1.w = (selmask&128u) ? e[7]*inv : 0.f;
  float* outp = H + (size_t)row*512 + lane*8;
  *(float4*)outp     = o0;
  *(float4*)(outp+4) = o1;
}

// ============================================================================
extern "C" void kernel_launch(void* const* d_in, const int* in_sizes, int n_in,
                              void* d_out, int out_size, void* d_ws, size_t ws_size,
                              hipStream_t stream)
{
  const float* inputs = (const float*)d_in[0];
  const float* noise  = (const float*)d_in[1];
  const float* emu    = (const float*)d_in[2];
  const float* elsig  = (const float*)d_in[3];
  const float* Wq = (const float*)d_in[4];  const float* bq = (const float*)d_in[5];
  const float* Wk = (const float*)d_in[6];  const float* bk = (const float*)d_in[7];
  const float* Wv = (const float*)d_in[8];  const float* bv = (const float*)d_in[9];
  const float* W1 = (const float*)d_in[10]; const float* b1 = (const float*)d_in[11];
  const float* W2 = (const float*)d_in[12]; const float* b2 = (const float*)d_in[13];
  const float* g_in = (const float*)d_in[14]; const float* b_in = (const float*)d_in[15];
  const float* g_e  = (const float*)d_in[16]; const float* b_e  = (const float*)d_in[17];
  const int* knp = (const int*)d_in[18];
  const int* kep = (const int*)d_in[19];

  float* out = (float*)d_out;
  float* out_edges = out;                             // 512*1024
  float* out_H     = out + 512*1024;                  // 8192*512
  float* out_dots  = out + 512*1024 + 8192*512;       // 512*8192

  // ---- workspace (~112 MB peak, stream-ordered reuse) ----
  char* p = (char*)d_ws;
  const size_t MB = 1024ull*1024;
  u16* xh = (u16*)(p + 0*MB);            // x split, live to the end (dots_v)
  u16* xl = (u16*)(p + 16*MB);
  u16* kb = (u16*)(p + 32*MB);           // k bf16, dead after dots GEMM
  u16* vb = (u16*)(p + 48*MB);           // v bf16, dead after gather
  float* dotsvf = (float*)(p + 32*MB);   // dots_v fp32 (reuses kb region)
  // weights [64,88)
  u16* WkvTh = (u16*)(p + 64*MB);        // stacked [WkT;WvT], 2048x1024 (4MB)
  u16* WkTl  = (u16*)(p + 68*MB);
  u16* WqTh  = (u16*)(p + 70*MB);
  u16* Wqh   = (u16*)(p + 72*MB);  u16* Wql  = (u16*)(p + 74*MB);   // raw (no T)
  u16* W1Th  = (u16*)(p + 76*MB);  u16* W1Tl = (u16*)(p + 80*MB);
  u16* W2Th  = (u16*)(p + 84*MB);  u16* W2Tl = (u16*)(p + 86*MB);
  // small [88,102)
  u16* cath = (u16*)(p + 88*MB);  u16* catl = (u16*)(p + 90*MB);
  u16* qmb  = (u16*)(p + 92*MB);
  u16* h1h  = (u16*)(p + 93*MB);  u16* h1l  = (u16*)(p + 94*MB);
  u16* eoh  = (u16*)(p + 95*MB);  u16* eol  = (u16*)(p + 96*MB);
  u16* k2h  = (u16*)(p + 97*MB);  u16* k2l  = (u16*)(p + 98*MB);
  u16* Gth  = (u16*)(p + 99*MB);  u16* Gtl  = (u16*)(p + 100*MB);
  int*   tidx  = (int*)  (p + 101*MB);
  float* tw    = (float*)(p + 101*MB + 256*1024);
  float* biasv = (float*)(p + 101*MB + 512*1024);
  float* part  = (float*)(p + 104*MB);   // split-K partials: 4*512*1024*4 = 8MB

  hipMemsetAsync(tidx, 0, 512ull*128*4*2, stream);   // tidx + tw (contiguous)

  // fused weight prep (was 6 launches)
  prep_weights<<<7168,256,0,stream>>>(Wk, W1, W2, Wv, Wq,
                                      WkvTh, WkTl, W1Th, W1Tl, W2Th, W2Tl,
                                      WqTh, Wqh, Wql);
  // fused layernorms (was 2 launches)
  ln_all<<<8704,256,0,stream>>>(inputs, g_in, b_in, xh, xl,
                                noise, emu, elsig, g_e, b_e, cath, catl);

  const size_t MN = 512ull*1024;
  // --- dots chain (plain bf16; selection-tolerant) ---
  // k|v = relu(x@{Wk,Wv}+b): ONE launch, B stacked 2048 rows, grid (16,64)
  gemm_kv_128<<<dim3(16,64),256,0,stream>>>(xh,1024, WkvTh,1024, bk, bv,
                                            kb, vb, 1024);
  // qm = relu(cat@Wq+bq): M=512 -> 64-tile split-K4, grid (8,8,4)
  gemm1_64<false,4><<<dim3(8,8,4),256,0,stream>>>(cath,2048, WqTh,1024, nullptr, 1.f,
                                                  nullptr,nullptr, part, 1024,1024,512);
  reduce_epi<true,4><<<512,256,0,stream>>>(part, bq, 1.f, nullptr,nullptr, qmb,nullptr,
                                           MN, 1024, nullptr, nullptr);
  // dots = qm@k^T / 32 -> fp32 d_out: grid (8192/128, 512/128)
  gemm1_128<false><<<dim3(64,4),256,0,stream>>>(qmb,1024, kb,1024, nullptr, 0.03125f,
                                                nullptr,out_dots, 1024,8192);
  softmax_topk_a<<<512,256,0,stream>>>(out_dots, knp, tidx, tw);
  gather_updates<<<512,256,0,stream>>>(tidx, tw, knp, vb, cath, catl);

  // --- edges + H chain (split-bf16, fp32-class), all M=512 -> split-K4 ---
  gemm3_64<false,4><<<dim3(8,8,4),256,0,stream>>>(cath,catl,2048, W1Th,W1Tl,2048,
                                                  nullptr,1.f, nullptr,nullptr,nullptr,
                                                  part, 2048,1024,512);
  reduce_epi<true,4><<<512,256,0,stream>>>(part, b1, 1.f, h1h,h1l, nullptr,nullptr,
                                           MN, 1024, nullptr, nullptr);
  gemm3_64<false,4><<<dim3(8,8,4),256,0,stream>>>(h1h,h1l,1024, W2Th,W2Tl,1024,
                                                  nullptr,1.f, nullptr,nullptr,nullptr,
                                                  part, 1024,1024,512);
  reduce_epi<false,4><<<512,256,0,stream>>>(part, b2, 1.f, eoh,eol, nullptr,out_edges,
                                            MN, 1024, nullptr, nullptr);
  // k2 = relu(edges@Wk+bk); fused bias_v = dot(bq,k2_row)/32 per row
  gemm3_64<false,4><<<dim3(8,8,4),256,0,stream>>>(eoh,eol,1024, WkvTh,WkTl,1024,
                                                  nullptr,1.f, nullptr,nullptr,nullptr,
                                                  part, 1024,1024,512);
  reduce_epi<true,4><<<512,256,0,stream>>>(part, bk, 1.f, k2h,k2l, nullptr,nullptr,
                                           MN, 1024, bq, biasv);
  // Gt[m,e] = sum_d k2[m,d]*Wq[e,d]
  gemm3_64<false,4><<<dim3(8,8,4),256,0,stream>>>(k2h,k2l,1024, Wqh,Wql,1024,
                                                  nullptr,1.f, nullptr,nullptr,nullptr,
                                                  part, 1024,1024,512);
  reduce_epi<false,4><<<512,256,0,stream>>>(part, nullptr, 1.f, Gth,Gtl, nullptr,nullptr,
                                            MN, 1024, nullptr, nullptr);
  // dots_v = x@Gt^T / 32 + biasv : 128-tile, grid (512/128, 8192/128)
  gemm3_128<<<dim3(4,64),256,0,stream>>>(xh,xl,1024, Gth,Gtl,1024,
                                         biasv, 0.03125f, dotsvf, 1024,512);
  softmax_topk_h_wave<<<2048,256,0,stream>>>(dotsvf, kep, out_H);
}

// Round 10
// 383.784 us; speedup vs baseline: 1.1121x; 1.0888x over previous
//
#include <hip/hip_runtime.h>
#include <stdint.h>
#include <stddef.h>

typedef unsigned short u16;
typedef __bf16 bf16x8 __attribute__((ext_vector_type(8)));
typedef float f32x4 __attribute__((ext_vector_type(4)));

#define DEV __device__ __forceinline__

DEV float bf2f(u16 u){ union{uint32_t i; float f;} c; c.i=(uint32_t)u<<16; return c.f; }
DEV u16 f2bf(float f){ union{float f; uint32_t i;} c; c.f=f; uint32_t x=c.i;
  uint32_t r = x + 0x7FFFu + ((x>>16)&1u); return (u16)(r>>16); }
DEV uint32_t fmap(float f){ union{float f; uint32_t u;} c; c.f=f;
  return (c.u & 0x80000000u) ? ~c.u : (c.u | 0x80000000u); }
DEV float funmap(uint32_t u){ union{uint32_t u; float f;} c;
  c.u = (u & 0x80000000u) ? (u & 0x7FFFFFFFu) : ~u; return c.f; }
DEV void split2(float x, u16& h, u16& l){ h = f2bf(x); l = f2bf(x - bf2f(h)); }

// XCD-aware bijective block remap (T1). Valid when gridDim.x*gridDim.y % 8 == 0.
// Dispatch round-robins block id across 8 XCDs; remap so each XCD owns a
// CONTIGUOUS chunk of logical tiles -> neighbor tiles sharing A/B panels hit
// the same per-XCD L2. Pure index permutation (correctness-neutral).
DEV void xcd_swizzle(int& bx, int& by){
  const int gx = gridDim.x, nwg = gx * gridDim.y;
  const int b  = blockIdx.x + gx*blockIdx.y;
  const int sb = (b & 7)*(nwg >> 3) + (b >> 3);
  bx = sb % gx; by = sb / gx;
}

// ---- block reductions (256 threads = 4 waves) ----
DEV float bredsum(float v, float* buf, int tid){
  #pragma unroll
  for(int o=32;o;o>>=1) v += __shfl_down(v,o);
  __syncthreads();
  if((tid&63)==0) buf[tid>>6]=v;
  __syncthreads();
  return buf[0]+buf[1]+buf[2]+buf[3];
}
DEV float bredmax(float v, float* buf, int tid){
  #pragma unroll
  for(int o=32;o;o>>=1) v = fmaxf(v, __shfl_down(v,o));
  __syncthreads();
  if((tid&63)==0) buf[tid>>6]=v;
  __syncthreads();
  return fmaxf(fmaxf(buf[0],buf[1]),fmaxf(buf[2],buf[3]));
}
DEV int bredsumi(int v, int* buf, int tid){
  #pragma unroll
  for(int o=32;o;o>>=1) v += __shfl_down(v,o);
  __syncthreads();
  if((tid&63)==0) buf[tid>>6]=v;
  __syncthreads();
  return buf[0]+buf[1]+buf[2]+buf[3];
}

// ============================================================================
// 64x128-tile plain bf16 GEMM (small-M split-K cases). Reg-staged (R7-best).
// ============================================================================
template<bool RELU, int SK>
__global__ __launch_bounds__(256)
void gemm1_64(const u16* __restrict__ A, int lda,
              const u16* __restrict__ Bt, int ldb,
              const float* __restrict__ bias, float scale,
              u16* __restrict__ outb, float* __restrict__ outf,
              float* __restrict__ part,
              int K, int ldc, int M)
{
  __shared__ __align__(16) u16 As[64*32];
  __shared__ __align__(16) u16 Bs[128*32];
  const int tid = threadIdx.x, lane = tid&63, wave = tid>>6;
  const int m0 = blockIdx.y*64, n0 = blockIdx.x*128;
  const int wm = (wave>>1)*32, wn = (wave&1)*64;
  const int ml = lane&15, quad = lane>>4;
  const int ks = K / SK;
  const int kbeg = blockIdx.z * ks;
  const u16* pa  = A  + (size_t)(m0+(tid>>2))*lda + kbeg + (tid&3)*8;
  const u16* pb0 = Bt + (size_t)(n0+(tid>>2))*ldb + kbeg + (tid&3)*8;
  const u16* pb1 = Bt + (size_t)(n0+64+(tid>>2))*ldb + kbeg + (tid&3)*8;

  f32x4 acc[2][4];
  #pragma unroll
  for(int i=0;i<2;i++)
    #pragma unroll
    for(int j=0;j<4;j++) acc[i][j] = (f32x4){0.f,0.f,0.f,0.f};

  uint4 ra=*(const uint4*)pa, rb0=*(const uint4*)pb0, rb1=*(const uint4*)pb1;
  for(int k0=0;k0<ks;k0+=32){
    __syncthreads();
    *(uint4*)&As[tid*8]       = ra;
    *(uint4*)&Bs[tid*8]       = rb0;
    *(uint4*)&Bs[(256+tid)*8] = rb1;
    __syncthreads();
    if(k0+32<ks){
      ra  = *(const uint4*)(pa +k0+32);
      rb0 = *(const uint4*)(pb0+k0+32);
      rb1 = *(const uint4*)(pb1+k0+32);
    }
    bf16x8 af[2], bf[4];
    #pragma unroll
    for(int mi=0;mi<2;mi++) af[mi] = *(const bf16x8*)&As[(wm+mi*16+ml)*32 + quad*8];
    #pragma unroll
    for(int ni=0;ni<4;ni++) bf[ni] = *(const bf16x8*)&Bs[(wn+ni*16+ml)*32 + quad*8];
    #pragma unroll
    for(int mi=0;mi<2;mi++)
      #pragma unroll
      for(int ni=0;ni<4;ni++)
        acc[mi][ni] = __builtin_amdgcn_mfma_f32_16x16x32_bf16(af[mi], bf[ni], acc[mi][ni], 0,0,0);
  }
  // C/D: col = lane&15, row = quad*4 + reg  (m89-verified)
  #pragma unroll
  for(int mi=0;mi<2;mi++){
    const int rbase = m0 + wm + mi*16 + quad*4;
    #pragma unroll
    for(int ni=0;ni<4;ni++){
      const int col = n0 + wn + ni*16 + ml;
      if(SK==1){
        const float bv = bias ? bias[col] : 0.f;
        #pragma unroll
        for(int r=0;r<4;r++){
          float v = acc[mi][ni][r]*scale + bv;
          if(RELU) v = fmaxf(v, 0.f);
          const size_t idx = (size_t)(rbase + r)*ldc + col;
          if(outb) outb[idx] = f2bf(v);
          if(outf) outf[idx] = v;
        }
      }else{
        #pragma unroll
        for(int r=0;r<4;r++)
          part[((size_t)blockIdx.z*M + rbase + r)*ldc + col] = acc[mi][ni][r];
      }
    }
  }
}

// ============================================================================
// 128x128-tile plain bf16 GEMM. 4 waves, each 64x64 (acc[4][4]). Reg-staged.
// XCD-swizzled block mapping (requires nwg % 8 == 0).
// ============================================================================
template<bool RELU>
__global__ __launch_bounds__(256)
void gemm1_128(const u16* __restrict__ A, int lda,
               const u16* __restrict__ Bt, int ldb,
               const float* __restrict__ bias, float scale,
               u16* __restrict__ outb, float* __restrict__ outf,
               int K, int ldc)
{
  __shared__ __align__(16) u16 As[128*32];
  __shared__ __align__(16) u16 Bs[128*32];
  const int tid = threadIdx.x, lane = tid&63, wave = tid>>6;
  int bxs, bys; xcd_swizzle(bxs, bys);
  const int m0 = bys*128, n0 = bxs*128;
  const int wm = (wave>>1)*64, wn = (wave&1)*64;
  const int ml = lane&15, quad = lane>>4;
  const u16* pa0 = A  + (size_t)(m0+(tid>>2))*lda    + (tid&3)*8;
  const u16* pa1 = A  + (size_t)(m0+64+(tid>>2))*lda + (tid&3)*8;
  const u16* pb0 = Bt + (size_t)(n0+(tid>>2))*ldb    + (tid&3)*8;
  const u16* pb1 = Bt + (size_t)(n0+64+(tid>>2))*ldb + (tid&3)*8;

  f32x4 acc[4][4];
  #pragma unroll
  for(int i=0;i<4;i++)
    #pragma unroll
    for(int j=0;j<4;j++) acc[i][j] = (f32x4){0.f,0.f,0.f,0.f};

  uint4 ra0=*(const uint4*)pa0, ra1=*(const uint4*)pa1;
  uint4 rb0=*(const uint4*)pb0, rb1=*(const uint4*)pb1;
  for(int k0=0;k0<K;k0+=32){
    __syncthreads();
    *(uint4*)&As[tid*8]       = ra0;
    *(uint4*)&As[(256+tid)*8] = ra1;
    *(uint4*)&Bs[tid*8]       = rb0;
    *(uint4*)&Bs[(256+tid)*8] = rb1;
    __syncthreads();
    if(k0+32<K){
      ra0 = *(const uint4*)(pa0+k0+32);
      ra1 = *(const uint4*)(pa1+k0+32);
      rb0 = *(const uint4*)(pb0+k0+32);
      rb1 = *(const uint4*)(pb1+k0+32);
    }
    bf16x8 af[4], bf[4];
    #pragma unroll
    for(int mi=0;mi<4;mi++) af[mi] = *(const bf16x8*)&As[(wm+mi*16+ml)*32 + quad*8];
    #pragma unroll
    for(int ni=0;ni<4;ni++) bf[ni] = *(const bf16x8*)&Bs[(wn+ni*16+ml)*32 + quad*8];
    #pragma unroll
    for(int mi=0;mi<4;mi++)
      #pragma unroll
      for(int ni=0;ni<4;ni++)
        acc[mi][ni] = __builtin_amdgcn_mfma_f32_16x16x32_bf16(af[mi], bf[ni], acc[mi][ni], 0,0,0);
  }
  #pragma unroll
  for(int mi=0;mi<4;mi++){
    const int rbase = m0 + wm + mi*16 + quad*4;
    #pragma unroll
    for(int ni=0;ni<4;ni++){
      const int col = n0 + wn + ni*16 + ml;
      const float bv = bias ? bias[col] : 0.f;
      #pragma unroll
      for(int r=0;r<4;r++){
        float v = acc[mi][ni][r]*scale + bv;
        if(RELU) v = fmaxf(v, 0.f);
        const size_t idx = (size_t)(rbase + r)*ldc + col;
        if(outb) outb[idx] = f2bf(v);
        if(outf) outf[idx] = v;
      }
    }
  }
}

// ============================================================================
// Fused k|v GEMM: B = [WkT ; WvT] stacked (2048 rows). col<1024 -> kb (+bk),
// else -> vb (+bv). Both RELU. Reg-staged + XCD swizzle.
// ============================================================================
__global__ __launch_bounds__(256)
void gemm_kv_128(const u16* __restrict__ A, int lda,
                 const u16* __restrict__ Bt, int ldb,
                 const float* __restrict__ bk, const float* __restrict__ bv,
                 u16* __restrict__ kb, u16* __restrict__ vb, int K)
{
  __shared__ __align__(16) u16 As[128*32];
  __shared__ __align__(16) u16 Bs[128*32];
  const int tid = threadIdx.x, lane = tid&63, wave = tid>>6;
  int bxs, bys; xcd_swizzle(bxs, bys);
  const int m0 = bys*128, n0 = bxs*128;
  const int wm = (wave>>1)*64, wn = (wave&1)*64;
  const int ml = lane&15, quad = lane>>4;
  const u16* pa0 = A  + (size_t)(m0+(tid>>2))*lda    + (tid&3)*8;
  const u16* pa1 = A  + (size_t)(m0+64+(tid>>2))*lda + (tid&3)*8;
  const u16* pb0 = Bt + (size_t)(n0+(tid>>2))*ldb    + (tid&3)*8;
  const u16* pb1 = Bt + (size_t)(n0+64+(tid>>2))*ldb + (tid&3)*8;

  f32x4 acc[4][4];
  #pragma unroll
  for(int i=0;i<4;i++)
    #pragma unroll
    for(int j=0;j<4;j++) acc[i][j] = (f32x4){0.f,0.f,0.f,0.f};

  uint4 ra0=*(const uint4*)pa0, ra1=*(const uint4*)pa1;
  uint4 rb0=*(const uint4*)pb0, rb1=*(const uint4*)pb1;
  for(int k0=0;k0<K;k0+=32){
    __syncthreads();
    *(uint4*)&As[tid*8]       = ra0;
    *(uint4*)&As[(256+tid)*8] = ra1;
    *(uint4*)&Bs[tid*8]       = rb0;
    *(uint4*)&Bs[(256+tid)*8] = rb1;
    __syncthreads();
    if(k0+32<K){
      ra0 = *(const uint4*)(pa0+k0+32);
      ra1 = *(const uint4*)(pa1+k0+32);
      rb0 = *(const uint4*)(pb0+k0+32);
      rb1 = *(const uint4*)(pb1+k0+32);
    }
    bf16x8 af[4], bf[4];
    #pragma unroll
    for(int mi=0;mi<4;mi++) af[mi] = *(const bf16x8*)&As[(wm+mi*16+ml)*32 + quad*8];
    #pragma unroll
    for(int ni=0;ni<4;ni++) bf[ni] = *(const bf16x8*)&Bs[(wn+ni*16+ml)*32 + quad*8];
    #pragma unroll
    for(int mi=0;mi<4;mi++)
      #pragma unroll
      for(int ni=0;ni<4;ni++)
        acc[mi][ni] = __builtin_amdgcn_mfma_f32_16x16x32_bf16(af[mi], bf[ni], acc[mi][ni], 0,0,0);
  }
  #pragma unroll
  for(int mi=0;mi<4;mi++){
    const int rbase = m0 + wm + mi*16 + quad*4;
    #pragma unroll
    for(int ni=0;ni<4;ni++){
      const int col = n0 + wn + ni*16 + ml;      // 0..2047
      const bool isv = col >= 1024;
      const int c2 = col & 1023;
      const float bb = isv ? bv[c2] : bk[c2];
      u16* outp = isv ? vb : kb;
      #pragma unroll
      for(int r=0;r<4;r++){
        const float v = fmaxf(acc[mi][ni][r] + bb, 0.f);
        outp[(size_t)(rbase + r)*1024 + c2] = f2bf(v);
      }
    }
  }
}

// ============================================================================
// 64x128-tile split-bf16 GEMM (small-M split-K cases). Reg-staged.
// ============================================================================
template<bool RELU, int SK>
__global__ __launch_bounds__(256)
void gemm3_64(const u16* __restrict__ Ah, const u16* __restrict__ Al, int lda,
              const u16* __restrict__ Bh, const u16* __restrict__ Bl, int ldb,
              const float* __restrict__ bias, float scale,
              u16* __restrict__ outh, u16* __restrict__ outl,
              float* __restrict__ outf, float* __restrict__ part,
              int K, int ldc, int M)
{
  __shared__ __align__(16) u16 AsH[64*32];
  __shared__ __align__(16) u16 AsL[64*32];
  __shared__ __align__(16) u16 BsH[128*32];
  __shared__ __align__(16) u16 BsL[128*32];
  const int tid = threadIdx.x, lane = tid&63, wave = tid>>6;
  const int m0 = blockIdx.y*64, n0 = blockIdx.x*128;
  const int wm = (wave>>1)*32, wn = (wave&1)*64;
  const int ml = lane&15, quad = lane>>4;
  const int ks = K / SK;
  const int kbeg = blockIdx.z * ks;
  const size_t ao  = (size_t)(m0+(tid>>2))*lda + kbeg + (tid&3)*8;
  const size_t bo0 = (size_t)(n0+(tid>>2))*ldb + kbeg + (tid&3)*8;
  const size_t bo1 = (size_t)(n0+64+(tid>>2))*ldb + kbeg + (tid&3)*8;

  f32x4 acc[2][4];
  #pragma unroll
  for(int i=0;i<2;i++)
    #pragma unroll
    for(int j=0;j<4;j++) acc[i][j] = (f32x4){0.f,0.f,0.f,0.f};

  uint4 rah=*(const uint4*)(Ah+ao),  ral=*(const uint4*)(Al+ao);
  uint4 rbh0=*(const uint4*)(Bh+bo0), rbl0=*(const uint4*)(Bl+bo0);
  uint4 rbh1=*(const uint4*)(Bh+bo1), rbl1=*(const uint4*)(Bl+bo1);
  for(int k0=0;k0<ks;k0+=32){
    __syncthreads();
    *(uint4*)&AsH[tid*8]       = rah;
    *(uint4*)&AsL[tid*8]       = ral;
    *(uint4*)&BsH[tid*8]       = rbh0;
    *(uint4*)&BsL[tid*8]       = rbl0;
    *(uint4*)&BsH[(256+tid)*8] = rbh1;
    *(uint4*)&BsL[(256+tid)*8] = rbl1;
    __syncthreads();
    if(k0+32<ks){
      const int s = k0+32;
      rah =*(const uint4*)(Ah+ao +s); ral =*(const uint4*)(Al+ao +s);
      rbh0=*(const uint4*)(Bh+bo0+s); rbl0=*(const uint4*)(Bl+bo0+s);
      rbh1=*(const uint4*)(Bh+bo1+s); rbl1=*(const uint4*)(Bl+bo1+s);
    }
    bf16x8 afh[2], afl[2], bfh[4], bfl[4];
    #pragma unroll
    for(int mi=0;mi<2;mi++){
      const int o = (wm+mi*16+ml)*32 + quad*8;
      afh[mi] = *(const bf16x8*)&AsH[o];
      afl[mi] = *(const bf16x8*)&AsL[o];
    }
    #pragma unroll
    for(int ni=0;ni<4;ni++){
      const int o = (wn+ni*16+ml)*32 + quad*8;
      bfh[ni] = *(const bf16x8*)&BsH[o];
      bfl[ni] = *(const bf16x8*)&BsL[o];
    }
    #pragma unroll
    for(int mi=0;mi<2;mi++)
      #pragma unroll
      for(int ni=0;ni<4;ni++){
        acc[mi][ni] = __builtin_amdgcn_mfma_f32_16x16x32_bf16(afh[mi], bfh[ni], acc[mi][ni], 0,0,0);
        acc[mi][ni] = __builtin_amdgcn_mfma_f32_16x16x32_bf16(afh[mi], bfl[ni], acc[mi][ni], 0,0,0);
        acc[mi][ni] = __builtin_amdgcn_mfma_f32_16x16x32_bf16(afl[mi], bfh[ni], acc[mi][ni], 0,0,0);
      }
  }
  #pragma unroll
  for(int mi=0;mi<2;mi++){
    const int rbase = m0 + wm + mi*16 + quad*4;
    #pragma unroll
    for(int ni=0;ni<4;ni++){
      const int col = n0 + wn + ni*16 + ml;
      if(SK==1){
        const float bv = bias ? bias[col] : 0.f;
        #pragma unroll
        for(int r=0;r<4;r++){
          float v = acc[mi][ni][r]*scale + bv;
          if(RELU) v = fmaxf(v, 0.f);
          const size_t idx = (size_t)(rbase + r)*ldc + col;
          if(outh){ u16 h, l; split2(v, h, l); outh[idx] = h; outl[idx] = l; }
          if(outf) outf[idx] = v;
        }
      }else{
        #pragma unroll
        for(int r=0;r<4;r++)
          part[((size_t)blockIdx.z*M + rbase + r)*ldc + col] = acc[mi][ni][r];
      }
    }
  }
}

// ============================================================================
// 128x128-tile split-bf16 GEMM (fp32-class). 4 waves x 64x64, acc[4][4].
// Reg-staged + XCD swizzle.
// ============================================================================
__global__ __launch_bounds__(256)
void gemm3_128(const u16* __restrict__ Ah, const u16* __restrict__ Al, int lda,
               const u16* __restrict__ Bh, const u16* __restrict__ Bl, int ldb,
               const float* __restrict__ bias, float scale,
               float* __restrict__ outf, int K, int ldc)
{
  __shared__ __align__(16) u16 AsH[128*32];
  __shared__ __align__(16) u16 AsL[128*32];
  __shared__ __align__(16) u16 BsH[128*32];
  __shared__ __align__(16) u16 BsL[128*32];
  const int tid = threadIdx.x, lane = tid&63, wave = tid>>6;
  int bxs, bys; xcd_swizzle(bxs, bys);
  const int m0 = bys*128, n0 = bxs*128;
  const int wm = (wave>>1)*64, wn = (wave&1)*64;
  const int ml = lane&15, quad = lane>>4;
  const size_t ao0 = (size_t)(m0+(tid>>2))*lda    + (tid&3)*8;
  const size_t ao1 = (size_t)(m0+64+(tid>>2))*lda + (tid&3)*8;
  const size_t bo0 = (size_t)(n0+(tid>>2))*ldb    + (tid&3)*8;
  const size_t bo1 = (size_t)(n0+64+(tid>>2))*ldb + (tid&3)*8;

  f32x4 acc[4][4];
  #pragma unroll
  for(int i=0;i<4;i++)
    #pragma unroll
    for(int j=0;j<4;j++) acc[i][j] = (f32x4){0.f,0.f,0.f,0.f};

  uint4 rah0=*(const uint4*)(Ah+ao0), ral0=*(const uint4*)(Al+ao0);
  uint4 rah1=*(const uint4*)(Ah+ao1), ral1=*(const uint4*)(Al+ao1);
  uint4 rbh0=*(const uint4*)(Bh+bo0), rbl0=*(const uint4*)(Bl+bo0);
  uint4 rbh1=*(const uint4*)(Bh+bo1), rbl1=*(const uint4*)(Bl+bo1);
  for(int k0=0;k0<K;k0+=32){
    __syncthreads();
    *(uint4*)&AsH[tid*8]       = rah0;
    *(uint4*)&AsH[(256+tid)*8] = rah1;
    *(uint4*)&AsL[tid*8]       = ral0;
    *(uint4*)&AsL[(256+tid)*8] = ral1;
    *(uint4*)&BsH[tid*8]       = rbh0;
    *(uint4*)&BsH[(256+tid)*8] = rbh1;
    *(uint4*)&BsL[tid*8]       = rbl0;
    *(uint4*)&BsL[(256+tid)*8] = rbl1;
    __syncthreads();
    if(k0+32<K){
      const int s = k0+32;
      rah0=*(const uint4*)(Ah+ao0+s); ral0=*(const uint4*)(Al+ao0+s);
      rah1=*(const uint4*)(Ah+ao1+s); ral1=*(const uint4*)(Al+ao1+s);
      rbh0=*(const uint4*)(Bh+bo0+s); rbl0=*(const uint4*)(Bl+bo0+s);
      rbh1=*(const uint4*)(Bh+bo1+s); rbl1=*(const uint4*)(Bl+bo1+s);
    }
    bf16x8 afh[4], afl[4], bfh[4], bfl[4];
    #pragma unroll
    for(int mi=0;mi<4;mi++){
      const int o = (wm+mi*16+ml)*32 + quad*8;
      afh[mi] = *(const bf16x8*)&AsH[o];
      afl[mi] = *(const bf16x8*)&AsL[o];
    }
    #pragma unroll
    for(int ni=0;ni<4;ni++){
      const int o = (wn+ni*16+ml)*32 + quad*8;
      bfh[ni] = *(const bf16x8*)&BsH[o];
      bfl[ni] = *(const bf16x8*)&BsL[o];
    }
    #pragma unroll
    for(int mi=0;mi<4;mi++)
      #pragma unroll
      for(int ni=0;ni<4;ni++){
        acc[mi][ni] = __builtin_amdgcn_mfma_f32_16x16x32_bf16(afh[mi], bfh[ni], acc[mi][ni], 0,0,0);
        acc[mi][ni] = __builtin_amdgcn_mfma_f32_16x16x32_bf16(afh[mi], bfl[ni], acc[mi][ni], 0,0,0);
        acc[mi][ni] = __builtin_amdgcn_mfma_f32_16x16x32_bf16(afl[mi], bfh[ni], acc[mi][ni], 0,0,0);
      }
  }
  #pragma unroll
  for(int mi=0;mi<4;mi++){
    const int rbase = m0 + wm + mi*16 + quad*4;
    #pragma unroll
    for(int ni=0;ni<4;ni++){
      const int col = n0 + wn + ni*16 + ml;
      const float bv = bias ? bias[col] : 0.f;
      #pragma unroll
      for(int r=0;r<4;r++){
        const float v = acc[mi][ni][r]*scale + bv;
        outf[(size_t)(rbase + r)*ldc + col] = v;
      }
    }
  }
}

// ============================================================================
// reduce SK fp32 partials + bias/act -> split-bf16 / bf16 / fp32 outputs.
// Optional fused row-dot: bvout[row] = dot(bqv, rowvals)/32 (block == 1 row,
// valid when N==1024). Saves the separate bias_v launch.
// ============================================================================
template<bool RELU, int SK>
__global__ __launch_bounds__(256)
void reduce_epi(const float* __restrict__ part, const float* __restrict__ bias,
                float scale, u16* __restrict__ outh, u16* __restrict__ outl,
                u16* __restrict__ outb, float* __restrict__ outf,
                size_t MN, int N,
                const float* __restrict__ bqv, float* __restrict__ bvout)
{
  __shared__ float buf[4];
  const int tid = threadIdx.x;
  const size_t i = ((size_t)blockIdx.x*256 + tid)*4;
  float4 s = *(const float4*)(part + i);
  #pragma unroll
  for(int z=1; z<SK; z++){
    const float4 t = *(const float4*)(part + (size_t)z*MN + i);
    s.x += t.x; s.y += t.y; s.z += t.z; s.w += t.w;
  }
  const int col = (int)(i % (size_t)N);
  float4 bv = bias ? *(const float4*)(bias + col) : (float4){0.f,0.f,0.f,0.f};
  float v[4] = { s.x*scale + bv.x, s.y*scale + bv.y, s.z*scale + bv.z, s.w*scale + bv.w };
  if(RELU){
    #pragma unroll
    for(int j=0;j<4;j++) v[j] = fmaxf(v[j], 0.f);
  }
  if(outh){
    ushort4 h4, l4;
    split2(v[0], h4.x, l4.x); split2(v[1], h4.y, l4.y);
    split2(v[2], h4.z, l4.z); split2(v[3], h4.w, l4.w);
    *(ushort4*)(outh + i) = h4;
    *(ushort4*)(outl + i) = l4;
  }
  if(outb){
    ushort4 b4;
    b4.x=f2bf(v[0]); b4.y=f2bf(v[1]); b4.z=f2bf(v[2]); b4.w=f2bf(v[3]);
    *(ushort4*)(outb + i) = b4;
  }
  if(outf) *(float4*)(outf + i) = (float4){v[0],v[1],v[2],v[3]};
  if(bvout){   // uniform branch; block == one row (N==1024, 256 thr x 4)
    const float4 q = *(const float4*)(bqv + col);
    float d = q.x*v[0] + q.y*v[1] + q.z*v[2] + q.w*v[3];
    d = bredsum(d, buf, tid);
    if(tid==0) bvout[blockIdx.x] = d * 0.03125f;
  }
}

// ============================================================================
// Fused weight prep: all transposes + split conversions in ONE launch.
// block-id ranges: [0,1024) Wk->ts(WkvTh,WkTl) ; [1024,3072) W1->ts ;
// [3072,4096) W2->ts ; [4096,5120) Wv->tp(WkvTh+1M) ; [5120,6144) Wq->tp ;
// [6144,7168) Wq->split_convert.
// ============================================================================
DEV void dev_tsplit(const float* in, u16* oh, u16* ol, int R, int C,
                    int bx, int by, int tid, float (*tile)[33])
{
  const int tx = tid & 31, ty = tid >> 5;
  #pragma unroll
  for(int i=0;i<32;i+=8)
    tile[ty+i][tx] = in[(size_t)(by*32+ty+i)*C + bx*32 + tx];
  __syncthreads();
  #pragma unroll
  for(int i=0;i<32;i+=8){
    const float v = tile[tx][ty+i];
    u16 h, l; split2(v, h, l);
    const size_t o = (size_t)(bx*32+ty+i)*R + by*32 + tx;
    oh[o] = h; if(ol) ol[o] = l;
  }
}
__global__ __launch_bounds__(256)
void prep_weights(const float* __restrict__ Wk, const float* __restrict__ W1,
                  const float* __restrict__ W2, const float* __restrict__ Wv,
                  const float* __restrict__ Wq,
                  u16* __restrict__ WkvTh, u16* __restrict__ WkTl,
                  u16* __restrict__ W1Th,  u16* __restrict__ W1Tl,
                  u16* __restrict__ W2Th,  u16* __restrict__ W2Tl,
                  u16* __restrict__ WqTh,
                  u16* __restrict__ Wqh,   u16* __restrict__ Wql)
{
  __shared__ float tile[32][33];
  const int id = blockIdx.x, tid = threadIdx.x;
  if(id < 1024){
    dev_tsplit(Wk, WkvTh, WkTl, 1024, 1024, id&31, id>>5, tid, tile);
  }else if(id < 3072){
    const int l = id - 1024;
    dev_tsplit(W1, W1Th, W1Tl, 2048, 1024, l&31, l>>5, tid, tile);
  }else if(id < 4096){
    const int l = id - 3072;
    dev_tsplit(W2, W2Th, W2Tl, 1024, 1024, l&31, l>>5, tid, tile);
  }else if(id < 5120){
    const int l = id - 4096;
    dev_tsplit(Wv, WkvTh + 1024*1024, nullptr, 1024, 1024, l&31, l>>5, tid, tile);
  }else if(id < 6144){
    const int l = id - 5120;
    dev_tsplit(Wq, WqTh, nullptr, 1024, 1024, l&31, l>>5, tid, tile);
  }else{
    const int l = id - 6144;
    const int i = l*256 + tid;
    const float4 v = ((const float4*)Wq)[i];
    ushort4 h4, l4;
    split2(v.x, h4.x, l4.x); split2(v.y, h4.y, l4.y);
    split2(v.z, h4.z, l4.z); split2(v.w, h4.w, l4.w);
    ((ushort4*)Wqh)[i] = h4; ((ushort4*)Wql)[i] = l4;
  }
}

// ============================================================================
// Fused LayerNorms: blocks [0,8192) = input rows -> xh/xl (stride 1024);
// blocks [8192,8704) = edge rows (mu + exp(lsig)*noise) -> cath/catl (2048).
// ============================================================================
__global__ __launch_bounds__(256)
void ln_all(const float* __restrict__ in, const float* __restrict__ g,
            const float* __restrict__ bb, u16* __restrict__ outh,
            u16* __restrict__ outl,
            const float* __restrict__ noise, const float* __restrict__ mu,
            const float* __restrict__ lsig, const float* __restrict__ ge,
            const float* __restrict__ be, u16* __restrict__ cath,
            u16* __restrict__ catl)
{
  __shared__ float buf[4];
  const int tid = threadIdx.x;
  const bool edge = blockIdx.x >= 8192;
  const int row = edge ? (blockIdx.x - 8192) : blockIdx.x;
  float v0,v1,v2,v3;
  if(!edge){
    const float4 xv = ((const float4*)(in + (size_t)row*1024))[tid];
    v0=xv.x; v1=xv.y; v2=xv.z; v3=xv.w;
  }else{
    const float4 nv  = ((const float4*)(noise + (size_t)row*1024))[tid];
    const float4 muv = ((const float4*)mu)[tid];
    const float4 lsv = ((const float4*)lsig)[tid];
    v0 = muv.x + expf(lsv.x)*nv.x;
    v1 = muv.y + expf(lsv.y)*nv.y;
    v2 = muv.z + expf(lsv.z)*nv.z;
    v3 = muv.w + expf(lsv.w)*nv.w;
  }
  float s  = bredsum(v0+v1+v2+v3, buf, tid);
  float s2 = bredsum(v0*v0+v1*v1+v2*v2+v3*v3, buf, tid);
  const float mean = s * (1.f/1024.f);
  const float var  = s2 * (1.f/1024.f) - mean*mean;
  const float rs   = 1.f / sqrtf(var + 1e-5f);
  const float4 gv = ((const float4*)(edge?ge:g))[tid];
  const float4 bv = ((const float4*)(edge?be:bb))[tid];
  float o0 = (v0-mean)*rs*gv.x + bv.x;
  float o1 = (v1-mean)*rs*gv.y + bv.y;
  float o2 = (v2-mean)*rs*gv.z + bv.z;
  float o3 = (v3-mean)*rs*gv.w + bv.w;
  ushort4 oh, ol;
  split2(o0, oh.x, ol.x); split2(o1, oh.y, ol.y);
  split2(o2, oh.z, ol.z); split2(o3, oh.w, ol.w);
  u16* ph = edge ? cath : outh;
  u16* pl = edge ? catl : outl;
  const int ostride = edge ? 2048 : 1024;
  ((ushort4*)(ph + (size_t)row*ostride))[tid] = oh;
  ((ushort4*)(pl + (size_t)row*ostride))[tid] = ol;
}

// ============================================================================
// softmax(8192)+eps+renorm + top-k_n -> (idx, weight) pairs. 1 block/row.
// ============================================================================
#define SWZ(i) ((i) ^ (((((unsigned)(i))>>5)&7u)<<2))
__global__ __launch_bounds__(256)
void softmax_topk_a(const float* __restrict__ dots, const int* __restrict__ knp,
                    int* __restrict__ tidx, float* __restrict__ tw)
{
  const int NC = 8192;
  __shared__ __align__(16) uint32_t us[8192];
  __shared__ float fbuf[4];
  __shared__ int ibuf[4];
  __shared__ int scan[256];
  __shared__ uint32_t hist[256];
  __shared__ uint32_t bcast;
  __shared__ int slot_ctr;
  const int row = blockIdx.x, tid = threadIdx.x;
  const int lane = tid & 63, wave = tid >> 6;
  const float* x = dots + (size_t)row * NC;

  float mx = -3.4e38f;
  #pragma unroll
  for(int it=0; it<8; ++it){
    const int i = (tid + it*256)*4;
    const float4 f = *(const float4*)(x + i);
    mx = fmaxf(fmaxf(mx, fmaxf(f.x,f.y)), fmaxf(f.z,f.w));
    uint4 u; u.x=fmap(f.x); u.y=fmap(f.y); u.z=fmap(f.z); u.w=fmap(f.w);
    *(uint4*)&us[SWZ(i)] = u;
  }
  mx = bredmax(mx, fbuf, tid);

  float se = 0.f;
  #pragma unroll
  for(int it=0; it<8; ++it){
    const int i = (tid + it*256)*4;
    const uint4 u = *(const uint4*)&us[SWZ(i)];
    se += expf(funmap(u.x)-mx) + expf(funmap(u.y)-mx)
        + expf(funmap(u.z)-mx) + expf(funmap(u.w)-mx);
  }
  se = bredsum(se, fbuf, tid);
  const float T = 1.f + (float)NC * 1e-8f;

  const int k = knp[0];
  const int base = tid*32;

  uint32_t prefix = 0;
  int remaining = k;
  #pragma unroll
  for(int shift=24; shift>=0; shift-=8){
    hist[tid] = 0;
    __syncthreads();
    const uint32_t himask = (shift==24) ? 0u : (0xFFFFFFFFu << (shift+8));
    #pragma unroll
    for(int j=0;j<32;j+=4){
      const uint4 u4 = *(const uint4*)&us[SWZ(base+j)];
      const uint32_t uu[4] = {u4.x,u4.y,u4.z,u4.w};
      #pragma unroll
      for(int t=0;t<4;t++)
        if((uu[t] & himask) == prefix) atomicAdd(&hist[(uu[t]>>shift)&255u], 1u);
    }
    __syncthreads();
    if(wave==0){
      const uint32_t h0=hist[4*lane], h1=hist[4*lane+1],
                     h2=hist[4*lane+2], h3=hist[4*lane+3];
      const uint32_t s3=h3, s2=h2+s3, s1=h1+s2, s0=h0+s1;
      uint32_t tsum = s0;
      #pragma unroll
      for(int o=1;o<64;o<<=1){
        const uint32_t vv = __shfl_down(tsum, o);
        if(lane + o < 64) tsum += vv;
      }
      const uint32_t excl = tsum - s0;
      const uint32_t r = (uint32_t)remaining;
      int cand = -1; uint32_t gsel = 0;
      if     (s3+excl >= r){ cand = 4*lane+3; gsel = excl; }
      else if(s2+excl >= r){ cand = 4*lane+2; gsel = s3+excl; }
      else if(s1+excl >= r){ cand = 4*lane+1; gsel = s2+excl; }
      else if(s0+excl >= r){ cand = 4*lane+0; gsel = s1+excl; }
      int bestc = cand; uint32_t bestg = gsel;
      #pragma unroll
      for(int o=32;o;o>>=1){
        const int oc = __shfl_xor(bestc, o);
        const uint32_t og = __shfl_xor(bestg, o);
        if(oc > bestc){ bestc = oc; bestg = og; }
      }
      if(lane==0) bcast = (uint32_t)bestc;
      remaining -= (int)bestg;
    }
    __syncthreads();
    prefix |= bcast << shift;
  }
  const uint32_t uth = prefix;

  int gt = 0, eq = 0;
  #pragma unroll
  for(int j=0;j<32;j+=4){
    const uint4 u4 = *(const uint4*)&us[SWZ(base+j)];
    gt += (u4.x>uth)+(u4.y>uth)+(u4.z>uth)+(u4.w>uth);
    eq += (u4.x==uth)+(u4.y==uth)+(u4.z==uth)+(u4.w==uth);
  }
  const int c1 = bredsumi(gt, ibuf, tid);
  __syncthreads();
  scan[tid] = eq;
  __syncthreads();
  #pragma unroll
  for(int o=1;o<256;o<<=1){
    int t = (tid>=o) ? scan[tid-o] : 0;
    __syncthreads();
    scan[tid] += t;
    __syncthreads();
  }
  int eq_rank = scan[tid] - eq;
  const int budget = k - c1;
  if(tid==0) slot_ctr = 0;
  __syncthreads();
  #pragma unroll 2
  for(int j=0;j<32;j+=4){
    const uint4 u4 = *(const uint4*)&us[SWZ(base+j)];
    const uint32_t uu[4] = {u4.x,u4.y,u4.z,u4.w};
    #pragma unroll
    for(int t=0;t<4;t++){
      const uint32_t u = uu[t];
      bool sel = (u > uth);
      if(u == uth){ sel = (eq_rank < budget); eq_rank++; }
      if(sel){
        const int s = atomicAdd(&slot_ctr, 1);
        const float f = funmap(u);
        const float w = (expf(f - mx)/se + 1e-8f) / T;
        if(s < 128){ tidx[row*128 + s] = base + j + t; tw[row*128 + s] = w; }
      }
    }
  }
}

// updates[row] = sum_j w_j * v[idx_j] (v bf16) ; split-bf16 into cat[:,1024:]
__global__ __launch_bounds__(256)
void gather_updates(const int* __restrict__ tidx, const float* __restrict__ tw,
                    const int* __restrict__ knp, const u16* __restrict__ v,
                    u16* __restrict__ cath, u16* __restrict__ catl)
{
  __shared__ int   idx_s[128];
  __shared__ float w_s[128];
  const int row = blockIdx.x, tid = threadIdx.x;
  const int kk = knp[0];
  if(tid < 128){
    idx_s[tid] = (tid < kk) ? (tidx[row*128+tid] & 8191) : 0;
    w_s[tid]   = (tid < kk) ? tw[row*128+tid] : 0.f;
  }
  __syncthreads();
  const int c = tid*4;
  float a0=0,a1=0,a2=0,a3=0;
  for(int j=0;j<kk && j<128;j++){
    const ushort4 vv = *(const ushort4*)&v[(size_t)idx_s[j]*1024 + c];
    const float w = w_s[j];
    a0 += w*bf2f(vv.x); a1 += w*bf2f(vv.y); a2 += w*bf2f(vv.z); a3 += w*bf2f(vv.w);
  }
  ushort4 oh, ol;
  split2(a0, oh.x, ol.x); split2(a1, oh.y, ol.y);
  split2(a2, oh.z, ol.z); split2(a3, oh.w, ol.w);
  ((ushort4*)(cath + (size_t)row*2048 + 1024))[tid] = oh;
  ((ushort4*)(catl + (size_t)row*2048 + 1024))[tid] = ol;
}

// ============================================================================
// H: softmax over 512 + top-k_e mask, one WAVE per row (4 rows/block).
// ============================================================================
__global__ __launch_bounds__(256)
void softmax_topk_h_wave(const float* __restrict__ dv, const int* __restrict__ kep,
                         float* __restrict__ H)
{
  const int wave = threadIdx.x >> 6, lane = threadIdx.x & 63;
  const int row = blockIdx.x*4 + wave;
  const float* x = dv + (size_t)row*512 + lane*8;
  const float4 a = *(const float4*)x;
  const float4 b = *(const float4*)(x+4);
  float vals[8] = {a.x,a.y,a.z,a.w,b.x,b.y,b.z,b.w};

  float mx = vals[0];
  #pragma unroll
  for(int j=1;j<8;j++) mx = fmaxf(mx, vals[j]);
  #pragma unroll
  for(int o=32;o;o>>=1) mx = fmaxf(mx, __shfl_xor(mx, o));
  float e[8], se = 0.f;
  #pragma unroll
  for(int j=0;j<8;j++){ e[j] = expf(vals[j]-mx); se += e[j]; }
  #pragma unroll
  for(int o=32;o;o>>=1) se += __shfl_xor(se, o);
  const float inv = 1.f/se;

  const int k = kep[0];
  unsigned int selmask = 0;
  for(int r=0;r<k;r++){
    unsigned long long best = 0;
    #pragma unroll
    for(int j=0;j<8;j++){
      if(!((selmask>>j)&1u)){
        const unsigned long long key =
          ((unsigned long long)fmap(vals[j]) << 9) | (unsigned long long)(511 - (lane*8+j));
        if(key > best) best = key;
      }
    }
    #pragma unroll
    for(int o=32;o;o>>=1){
      const unsigned long long other = __shfl_xor(best, o);
      if(other > best) best = other;
    }
    const int bidx = 511 - (int)(best & 511ull);
    if((bidx>>3) == lane) selmask |= 1u << (bidx & 7);
  }

  float4 o0, o1;
  o0.x = (selmask&  1u) ? e[0]*inv : 0.f;
  o0.y = (selmask&  2u) ? e[1]*inv : 0.f;
  o0.z = (selmask&  4u) ? e[2]*inv : 0.f;
  o0.w = (selmask&  8u) ? e[3]*inv : 0.f;
  o1.x = (selmask& 16u) ? e[4]*inv : 0.f;
  o1.y = (selmask& 32u) ? e[5]*inv : 0.f;
  o1.z = (selmask& 64u) ? e[6]*inv : 0.f;
  o1.w = (selmask&128u) ? e[7]*inv : 0.f;
  float* outp = H + (size_t)row*512 + lane*8;
  *(float4*)outp     = o0;
  *(float4*)(outp+4) = o1;
}

// ============================================================================
extern "C" void kernel_launch(void* const* d_in, const int* in_sizes, int n_in,
                              void* d_out, int out_size, void* d_ws, size_t ws_size,
                              hipStream_t stream)
{
  const float* inputs = (const float*)d_in[0];
  const float* noise  = (const float*)d_in[1];
  const float* emu    = (const float*)d_in[2];
  const float* elsig  = (const float*)d_in[3];
  const float* Wq = (const float*)d_in[4];  const float* bq = (const float*)d_in[5];
  const float* Wk = (const float*)d_in[6];  const float* bk = (const float*)d_in[7];
  const float* Wv = (const float*)d_in[8];  const float* bv = (const float*)d_in[9];
  const float* W1 = (const float*)d_in[10]; const float* b1 = (const float*)d_in[11];
  const float* W2 = (const float*)d_in[12]; const float* b2 = (const float*)d_in[13];
  const float* g_in = (const float*)d_in[14]; const float* b_in = (const float*)d_in[15];
  const float* g_e  = (const float*)d_in[16]; const float* b_e  = (const float*)d_in[17];
  const int* knp = (const int*)d_in[18];
  const int* kep = (const int*)d_in[19];

  float* out = (float*)d_out;
  float* out_edges = out;                             // 512*1024
  float* out_H     = out + 512*1024;                  // 8192*512
  float* out_dots  = out + 512*1024 + 8192*512;       // 512*8192

  // ---- workspace (~112 MB peak, stream-ordered reuse) ----
  char* p = (char*)d_ws;
  const size_t MB = 1024ull*1024;
  u16* xh = (u16*)(p + 0*MB);            // x split, live to the end (dots_v)
  u16* xl = (u16*)(p + 16*MB);
  u16* kb = (u16*)(p + 32*MB);           // k bf16, dead after dots GEMM
  u16* vb = (u16*)(p + 48*MB);           // v bf16, dead after gather
  float* dotsvf = (float*)(p + 32*MB);   // dots_v fp32 (reuses kb region)
  // weights [64,88)
  u16* WkvTh = (u16*)(p + 64*MB);        // stacked [WkT;WvT], 2048x1024 (4MB)
  u16* WkTl  = (u16*)(p + 68*MB);
  u16* WqTh  = (u16*)(p + 70*MB);
  u16* Wqh   = (u16*)(p + 72*MB);  u16* Wql  = (u16*)(p + 74*MB);   // raw (no T)
  u16* W1Th  = (u16*)(p + 76*MB);  u16* W1Tl = (u16*)(p + 80*MB);
  u16* W2Th  = (u16*)(p + 84*MB);  u16* W2Tl = (u16*)(p + 86*MB);
  // small [88,102)
  u16* cath = (u16*)(p + 88*MB);  u16* catl = (u16*)(p + 90*MB);
  u16* qmb  = (u16*)(p + 92*MB);
  u16* h1h  = (u16*)(p + 93*MB);  u16* h1l  = (u16*)(p + 94*MB);
  u16* eoh  = (u16*)(p + 95*MB);  u16* eol  = (u16*)(p + 96*MB);
  u16* k2h  = (u16*)(p + 97*MB);  u16* k2l  = (u16*)(p + 98*MB);
  u16* Gth  = (u16*)(p + 99*MB);  u16* Gtl  = (u16*)(p + 100*MB);
  int*   tidx  = (int*)  (p + 101*MB);
  float* tw    = (float*)(p + 101*MB + 256*1024);
  float* biasv = (float*)(p + 101*MB + 512*1024);
  float* part  = (float*)(p + 104*MB);   // split-K partials: 4*512*1024*4 = 8MB

  hipMemsetAsync(tidx, 0, 512ull*128*4*2, stream);   // tidx + tw (contiguous)

  // fused weight prep (was 6 launches)
  prep_weights<<<7168,256,0,stream>>>(Wk, W1, W2, Wv, Wq,
                                      WkvTh, WkTl, W1Th, W1Tl, W2Th, W2Tl,
                                      WqTh, Wqh, Wql);
  // fused layernorms (was 2 launches)
  ln_all<<<8704,256,0,stream>>>(inputs, g_in, b_in, xh, xl,
                                noise, emu, elsig, g_e, b_e, cath, catl);

  const size_t MN = 512ull*1024;
  // --- dots chain (plain bf16; selection-tolerant) ---
  // k|v = relu(x@{Wk,Wv}+b): ONE launch, B stacked 2048 rows, grid (16,64)
  gemm_kv_128<<<dim3(16,64),256,0,stream>>>(xh,1024, WkvTh,1024, bk, bv,
                                            kb, vb, 1024);
  // qm = relu(cat@Wq+bq): M=512 -> 64-tile split-K4, grid (8,8,4)
  gemm1_64<false,4><<<dim3(8,8,4),256,0,stream>>>(cath,2048, WqTh,1024, nullptr, 1.f,
                                                  nullptr,nullptr, part, 1024,1024,512);
  reduce_epi<true,4><<<512,256,0,stream>>>(part, bq, 1.f, nullptr,nullptr, qmb,nullptr,
                                           MN, 1024, nullptr, nullptr);
  // dots = qm@k^T / 32 -> fp32 d_out: grid (8192/128, 512/128)
  gemm1_128<false><<<dim3(64,4),256,0,stream>>>(qmb,1024, kb,1024, nullptr, 0.03125f,
                                                nullptr,out_dots, 1024,8192);
  softmax_topk_a<<<512,256,0,stream>>>(out_dots, knp, tidx, tw);
  gather_updates<<<512,256,0,stream>>>(tidx, tw, knp, vb, cath, catl);

  // --- edges + H chain (split-bf16, fp32-class), all M=512 -> split-K4 ---
  gemm3_64<false,4><<<dim3(8,8,4),256,0,stream>>>(cath,catl,2048, W1Th,W1Tl,2048,
                                                  nullptr,1.f, nullptr,nullptr,nullptr,
                                                  part, 2048,1024,512);
  reduce_epi<true,4><<<512,256,0,stream>>>(part, b1, 1.f, h1h,h1l, nullptr,nullptr,
                                           MN, 1024, nullptr, nullptr);
  gemm3_64<false,4><<<dim3(8,8,4),256,0,stream>>>(h1h,h1l,1024, W2Th,W2Tl,1024,
                                                  nullptr,1.f, nullptr,nullptr,nullptr,
                                                  part, 1024,1024,512);
  reduce_epi<false,4><<<512,256,0,stream>>>(part, b2, 1.f, eoh,eol, nullptr,out_edges,
                                            MN, 1024, nullptr, nullptr);
  // k2 = relu(edges@Wk+bk); fused bias_v = dot(bq,k2_row)/32 per row
  gemm3_64<false,4><<<dim3(8,8,4),256,0,stream>>>(eoh,eol,1024, WkvTh,WkTl,1024,
                                                  nullptr,1.f, nullptr,nullptr,nullptr,
                                                  part, 1024,1024,512);
  reduce_epi<true,4><<<512,256,0,stream>>>(part, bk, 1.f, k2h,k2l, nullptr,nullptr,
                                           MN, 1024, bq, biasv);
  // Gt[m,e] = sum_d k2[m,d]*Wq[e,d]
  gemm3_64<false,4><<<dim3(8,8,4),256,0,stream>>>(k2h,k2l,1024, Wqh,Wql,1024,
                                                  nullptr,1.f, nullptr,nullptr,nullptr,
                                                  part, 1024,1024,512);
  reduce_epi<false,4><<<512,256,0,stream>>>(part, nullptr, 1.f, Gth,Gtl, nullptr,nullptr,
                                            MN, 1024, nullptr, nullptr);
  // dots_v = x@Gt^T / 32 + biasv : 128-tile, grid (512/128, 8192/128)
  gemm3_128<<<dim3(4,64),256,0,stream>>>(xh,xl,1024, Gth,Gtl,1024,
                                         biasv, 0.03125f, dotsvf, 1024,512);
  softmax_topk_h_wave<<<2048,256,0,stream>>>(dotsvf, kep, out_H);
}

// Round 11
// 378.721 us; speedup vs baseline: 1.1270x; 1.0134x over previous
//
#include <hip/hip_runtime.h>
#include <stdint.h>
#include <stddef.h>

typedef unsigned short u16;
typedef uint32_t u32;
typedef __bf16 bf16x8 __attribute__((ext_vector_type(8)));
typedef float f32x4 __attribute__((ext_vector_type(4)));

#define DEV __device__ __forceinline__

// Async global->LDS, 16B/lane; HW dest = wave-uniform base + lane*16 (our
// computed per-lane dests satisfy this; verified by derivation: dst bytes are
// U0*16 + lane*16 with wave-uniform U0).
#define GLD16(g, l) __builtin_amdgcn_global_load_lds( \
    (const __attribute__((address_space(1))) u32*)(g), \
    (__attribute__((address_space(3))) u32*)(l), 16, 0, 0)

DEV float bf2f(u16 u){ union{uint32_t i; float f;} c; c.i=(uint32_t)u<<16; return c.f; }
DEV u16 f2bf(float f){ union{float f; uint32_t i;} c; c.f=f; uint32_t x=c.i;
  uint32_t r = x + 0x7FFFu + ((x>>16)&1u); return (u16)(r>>16); }
DEV uint32_t fmap(float f){ union{float f; uint32_t u;} c; c.f=f;
  return (c.u & 0x80000000u) ? ~c.u : (c.u | 0x80000000u); }
DEV float funmap(uint32_t u){ union{uint32_t u; float f;} c;
  c.u = (u & 0x80000000u) ? (u & 0x7FFFFFFFu) : ~u; return c.f; }
DEV void split2(float x, u16& h, u16& l){ h = f2bf(x); l = f2bf(x - bf2f(h)); }

// XCD-aware bijective block remap (T1). Valid when gridDim.x*gridDim.y % 8 == 0.
DEV void xcd_swizzle(int& bx, int& by){
  const int gx = gridDim.x, nwg = gx * gridDim.y;
  const int b  = blockIdx.x + gx*blockIdx.y;
  const int sb = (b & 7)*(nwg >> 3) + (b >> 3);
  bx = sb % gx; by = sb / gx;
}

// ---- block reductions (256 threads = 4 waves) ----
DEV float bredsum(float v, float* buf, int tid){
  #pragma unroll
  for(int o=32;o;o>>=1) v += __shfl_down(v,o);
  __syncthreads();
  if((tid&63)==0) buf[tid>>6]=v;
  __syncthreads();
  return buf[0]+buf[1]+buf[2]+buf[3];
}
DEV float bredmax(float v, float* buf, int tid){
  #pragma unroll
  for(int o=32;o;o>>=1) v = fmaxf(v, __shfl_down(v,o));
  __syncthreads();
  if((tid&63)==0) buf[tid>>6]=v;
  __syncthreads();
  return fmaxf(fmaxf(buf[0],buf[1]),fmaxf(buf[2],buf[3]));
}
DEV int bredsumi(int v, int* buf, int tid){
  #pragma unroll
  for(int o=32;o;o>>=1) v += __shfl_down(v,o);
  __syncthreads();
  if((tid&63)==0) buf[tid>>6]=v;
  __syncthreads();
  return buf[0]+buf[1]+buf[2]+buf[3];
}

// ============================================================================
// 64x128-tile plain bf16 GEMM (small-M split-K cases). Reg-staged (R7-best).
// ============================================================================
template<bool RELU, int SK>
__global__ __launch_bounds__(256)
void gemm1_64(const u16* __restrict__ A, int lda,
              const u16* __restrict__ Bt, int ldb,
              const float* __restrict__ bias, float scale,
              u16* __restrict__ outb, float* __restrict__ outf,
              float* __restrict__ part,
              int K, int ldc, int M)
{
  __shared__ __align__(16) u16 As[64*32];
  __shared__ __align__(16) u16 Bs[128*32];
  const int tid = threadIdx.x, lane = tid&63, wave = tid>>6;
  const int m0 = blockIdx.y*64, n0 = blockIdx.x*128;
  const int wm = (wave>>1)*32, wn = (wave&1)*64;
  const int ml = lane&15, quad = lane>>4;
  const int ks = K / SK;
  const int kbeg = blockIdx.z * ks;
  const u16* pa  = A  + (size_t)(m0+(tid>>2))*lda + kbeg + (tid&3)*8;
  const u16* pb0 = Bt + (size_t)(n0+(tid>>2))*ldb + kbeg + (tid&3)*8;
  const u16* pb1 = Bt + (size_t)(n0+64+(tid>>2))*ldb + kbeg + (tid&3)*8;

  f32x4 acc[2][4];
  #pragma unroll
  for(int i=0;i<2;i++)
    #pragma unroll
    for(int j=0;j<4;j++) acc[i][j] = (f32x4){0.f,0.f,0.f,0.f};

  uint4 ra=*(const uint4*)pa, rb0=*(const uint4*)pb0, rb1=*(const uint4*)pb1;
  for(int k0=0;k0<ks;k0+=32){
    __syncthreads();
    *(uint4*)&As[tid*8]       = ra;
    *(uint4*)&Bs[tid*8]       = rb0;
    *(uint4*)&Bs[(256+tid)*8] = rb1;
    __syncthreads();
    if(k0+32<ks){
      ra  = *(const uint4*)(pa +k0+32);
      rb0 = *(const uint4*)(pb0+k0+32);
      rb1 = *(const uint4*)(pb1+k0+32);
    }
    bf16x8 af[2], bf[4];
    #pragma unroll
    for(int mi=0;mi<2;mi++) af[mi] = *(const bf16x8*)&As[(wm+mi*16+ml)*32 + quad*8];
    #pragma unroll
    for(int ni=0;ni<4;ni++) bf[ni] = *(const bf16x8*)&Bs[(wn+ni*16+ml)*32 + quad*8];
    #pragma unroll
    for(int mi=0;mi<2;mi++)
      #pragma unroll
      for(int ni=0;ni<4;ni++)
        acc[mi][ni] = __builtin_amdgcn_mfma_f32_16x16x32_bf16(af[mi], bf[ni], acc[mi][ni], 0,0,0);
  }
  // C/D: col = lane&15, row = quad*4 + reg  (m89-verified)
  #pragma unroll
  for(int mi=0;mi<2;mi++){
    const int rbase = m0 + wm + mi*16 + quad*4;
    #pragma unroll
    for(int ni=0;ni<4;ni++){
      const int col = n0 + wn + ni*16 + ml;
      if(SK==1){
        const float bv = bias ? bias[col] : 0.f;
        #pragma unroll
        for(int r=0;r<4;r++){
          float v = acc[mi][ni][r]*scale + bv;
          if(RELU) v = fmaxf(v, 0.f);
          const size_t idx = (size_t)(rbase + r)*ldc + col;
          if(outb) outb[idx] = f2bf(v);
          if(outf) outf[idx] = v;
        }
      }else{
        #pragma unroll
        for(int r=0;r<4;r++)
          part[((size_t)blockIdx.z*M + rbase + r)*ldc + col] = acc[mi][ni][r];
      }
    }
  }
}

// ============================================================================
// 128x128-tile plain bf16 GEMM. Reg-staged + XCD swizzle.
// ============================================================================
template<bool RELU>
__global__ __launch_bounds__(256)
void gemm1_128(const u16* __restrict__ A, int lda,
               const u16* __restrict__ Bt, int ldb,
               const float* __restrict__ bias, float scale,
               u16* __restrict__ outb, float* __restrict__ outf,
               int K, int ldc)
{
  __shared__ __align__(16) u16 As[128*32];
  __shared__ __align__(16) u16 Bs[128*32];
  const int tid = threadIdx.x, lane = tid&63, wave = tid>>6;
  int bxs, bys; xcd_swizzle(bxs, bys);
  const int m0 = bys*128, n0 = bxs*128;
  const int wm = (wave>>1)*64, wn = (wave&1)*64;
  const int ml = lane&15, quad = lane>>4;
  const u16* pa0 = A  + (size_t)(m0+(tid>>2))*lda    + (tid&3)*8;
  const u16* pa1 = A  + (size_t)(m0+64+(tid>>2))*lda + (tid&3)*8;
  const u16* pb0 = Bt + (size_t)(n0+(tid>>2))*ldb    + (tid&3)*8;
  const u16* pb1 = Bt + (size_t)(n0+64+(tid>>2))*ldb + (tid&3)*8;

  f32x4 acc[4][4];
  #pragma unroll
  for(int i=0;i<4;i++)
    #pragma unroll
    for(int j=0;j<4;j++) acc[i][j] = (f32x4){0.f,0.f,0.f,0.f};

  uint4 ra0=*(const uint4*)pa0, ra1=*(const uint4*)pa1;
  uint4 rb0=*(const uint4*)pb0, rb1=*(const uint4*)pb1;
  for(int k0=0;k0<K;k0+=32){
    __syncthreads();
    *(uint4*)&As[tid*8]       = ra0;
    *(uint4*)&As[(256+tid)*8] = ra1;
    *(uint4*)&Bs[tid*8]       = rb0;
    *(uint4*)&Bs[(256+tid)*8] = rb1;
    __syncthreads();
    if(k0+32<K){
      ra0 = *(const uint4*)(pa0+k0+32);
      ra1 = *(const uint4*)(pa1+k0+32);
      rb0 = *(const uint4*)(pb0+k0+32);
      rb1 = *(const uint4*)(pb1+k0+32);
    }
    bf16x8 af[4], bf[4];
    #pragma unroll
    for(int mi=0;mi<4;mi++) af[mi] = *(const bf16x8*)&As[(wm+mi*16+ml)*32 + quad*8];
    #pragma unroll
    for(int ni=0;ni<4;ni++) bf[ni] = *(const bf16x8*)&Bs[(wn+ni*16+ml)*32 + quad*8];
    #pragma unroll
    for(int mi=0;mi<4;mi++)
      #pragma unroll
      for(int ni=0;ni<4;ni++)
        acc[mi][ni] = __builtin_amdgcn_mfma_f32_16x16x32_bf16(af[mi], bf[ni], acc[mi][ni], 0,0,0);
  }
  #pragma unroll
  for(int mi=0;mi<4;mi++){
    const int rbase = m0 + wm + mi*16 + quad*4;
    #pragma unroll
    for(int ni=0;ni<4;ni++){
      const int col = n0 + wn + ni*16 + ml;
      const float bv = bias ? bias[col] : 0.f;
      #pragma unroll
      for(int r=0;r<4;r++){
        float v = acc[mi][ni][r]*scale + bv;
        if(RELU) v = fmaxf(v, 0.f);
        const size_t idx = (size_t)(rbase + r)*ldc + col;
        if(outb) outb[idx] = f2bf(v);
        if(outf) outf[idx] = v;
      }
    }
  }
}

// ============================================================================
// Fused k|v GEMM, 256x256 tile, 512 threads (8 waves: 2M x 4N, 128x64/wave).
// 4-slot LDS ring of 32-K sub-tiles (128 KB), GLD16 staging 3 tiles ahead,
// COUNTED vmcnt (never 0 in steady state) + raw barriers (T3/T4, m198-style:
// linear LDS, no swizzle). Ring safety: slot (t+3)&3 == (t-1)&3, whose last
// read ended at the previous iteration's end-barrier; vmcnt ladder guarantees
// tile t's loads landed before BAR1; barrier collectivizes per-thread waits.
// ============================================================================
__global__ __launch_bounds__(512)
void gemm_kv_256(const u16* __restrict__ A, int lda,
                 const u16* __restrict__ Bt, int ldb,
                 const float* __restrict__ bk, const float* __restrict__ bv,
                 u16* __restrict__ kb, u16* __restrict__ vb, int K)
{
  __shared__ __align__(16) u16 As[4][256*32];   // 64 KB
  __shared__ __align__(16) u16 Bs[4][256*32];   // 64 KB
  const int tid = threadIdx.x, lane = tid&63, wave = tid>>6;
  int bxs, bys; xcd_swizzle(bxs, bys);          // grid (8,32): nwg=256 %8==0
  const int m0 = bys*256, n0 = bxs*256;
  const int wmw = (wave>>2)*128, wnw = (wave&3)*64;
  const int ml = lane&15, quad = lane>>4;
  // staging units: 256 rows x 4 colgroups(16B) = 1024 units, 2 per thread.
  const int r0 = tid>>2,        c0 = (tid&3)*8;
  const int r1 = (tid+512)>>2,  c1 = ((tid+512)&3)*8;
  const u16* pa0 = A  + (size_t)(m0+r0)*lda + c0;
  const u16* pa1 = A  + (size_t)(m0+r1)*lda + c1;
  const u16* pb0 = Bt + (size_t)(n0+r0)*ldb + c0;
  const u16* pb1 = Bt + (size_t)(n0+r1)*ldb + c1;
  const int d0 = r0*32 + c0, d1 = r1*32 + c1;

  f32x4 acc[8][4];
  #pragma unroll
  for(int i=0;i<8;i++)
    #pragma unroll
    for(int j=0;j<4;j++) acc[i][j] = (f32x4){0.f,0.f,0.f,0.f};

  #define KV_STAGE(t, s) do{                    \
    GLD16(pa0 + (t)*32, &As[s][d0]);            \
    GLD16(pa1 + (t)*32, &As[s][d1]);            \
    GLD16(pb0 + (t)*32, &Bs[s][d0]);            \
    GLD16(pb1 + (t)*32, &Bs[s][d1]); }while(0)

  KV_STAGE(0,0); KV_STAGE(1,1); KV_STAGE(2,2);
  const int NT = K >> 5;                        // 32
  for(int t=0;t<NT;t++){
    if(t+3<NT) KV_STAGE(t+3, (t+3)&3);
    const int rem = NT-1-t;                     // tiles issued after t still pending
    if(rem>=3)      asm volatile("s_waitcnt vmcnt(12)" ::: "memory");
    else if(rem==2) asm volatile("s_waitcnt vmcnt(8)"  ::: "memory");
    else if(rem==1) asm volatile("s_waitcnt vmcnt(4)"  ::: "memory");
    else            asm volatile("s_waitcnt vmcnt(0)"  ::: "memory");
    __builtin_amdgcn_s_barrier();               // BAR1: tile t resident for all
    const int s = t&3;
    bf16x8 af[8], bf[4];
    #pragma unroll
    for(int mi=0;mi<8;mi++) af[mi] = *(const bf16x8*)&As[s][(wmw+mi*16+ml)*32 + quad*8];
    #pragma unroll
    for(int ni=0;ni<4;ni++) bf[ni] = *(const bf16x8*)&Bs[s][(wnw+ni*16+ml)*32 + quad*8];
    #pragma unroll
    for(int mi=0;mi<8;mi++)
      #pragma unroll
      for(int ni=0;ni<4;ni++)
        acc[mi][ni] = __builtin_amdgcn_mfma_f32_16x16x32_bf16(af[mi], bf[ni], acc[mi][ni], 0,0,0);
    __builtin_amdgcn_s_barrier();               // BAR2: slot t&3 free for reuse
  }
  #undef KV_STAGE

  #pragma unroll
  for(int mi=0;mi<8;mi++){
    const int rbase = m0 + wmw + mi*16 + quad*4;
    #pragma unroll
    for(int ni=0;ni<4;ni++){
      const int col = n0 + wnw + ni*16 + ml;     // 0..2047
      const bool isv = col >= 1024;
      const int c2 = col & 1023;
      const float bb = isv ? bv[c2] : bk[c2];
      u16* outp = isv ? vb : kb;
      #pragma unroll
      for(int r=0;r<4;r++){
        const float v = fmaxf(acc[mi][ni][r] + bb, 0.f);
        outp[(size_t)(rbase + r)*1024 + c2] = f2bf(v);
      }
    }
  }
}

// ============================================================================
// 64x128-tile split-bf16 GEMM (small-M split-K cases). Reg-staged.
// ============================================================================
template<bool RELU, int SK>
__global__ __launch_bounds__(256)
void gemm3_64(const u16* __restrict__ Ah, const u16* __restrict__ Al, int lda,
              const u16* __restrict__ Bh, const u16* __restrict__ Bl, int ldb,
              const float* __restrict__ bias, float scale,
              u16* __restrict__ outh, u16* __restrict__ outl,
              float* __restrict__ outf, float* __restrict__ part,
              int K, int ldc, int M)
{
  __shared__ __align__(16) u16 AsH[64*32];
  __shared__ __align__(16) u16 AsL[64*32];
  __shared__ __align__(16) u16 BsH[128*32];
  __shared__ __align__(16) u16 BsL[128*32];
  const int tid = threadIdx.x, lane = tid&63, wave = tid>>6;
  const int m0 = blockIdx.y*64, n0 = blockIdx.x*128;
  const int wm = (wave>>1)*32, wn = (wave&1)*64;
  const int ml = lane&15, quad = lane>>4;
  const int ks = K / SK;
  const int kbeg = blockIdx.z * ks;
  const size_t ao  = (size_t)(m0+(tid>>2))*lda + kbeg + (tid&3)*8;
  const size_t bo0 = (size_t)(n0+(tid>>2))*ldb + kbeg + (tid&3)*8;
  const size_t bo1 = (size_t)(n0+64+(tid>>2))*ldb + kbeg + (tid&3)*8;

  f32x4 acc[2][4];
  #pragma unroll
  for(int i=0;i<2;i++)
    #pragma unroll
    for(int j=0;j<4;j++) acc[i][j] = (f32x4){0.f,0.f,0.f,0.f};

  uint4 rah=*(const uint4*)(Ah+ao),  ral=*(const uint4*)(Al+ao);
  uint4 rbh0=*(const uint4*)(Bh+bo0), rbl0=*(const uint4*)(Bl+bo0);
  uint4 rbh1=*(const uint4*)(Bh+bo1), rbl1=*(const uint4*)(Bl+bo1);
  for(int k0=0;k0<ks;k0+=32){
    __syncthreads();
    *(uint4*)&AsH[tid*8]       = rah;
    *(uint4*)&AsL[tid*8]       = ral;
    *(uint4*)&BsH[tid*8]       = rbh0;
    *(uint4*)&BsL[tid*8]       = rbl0;
    *(uint4*)&BsH[(256+tid)*8] = rbh1;
    *(uint4*)&BsL[(256+tid)*8] = rbl1;
    __syncthreads();
    if(k0+32<ks){
      const int s = k0+32;
      rah =*(const uint4*)(Ah+ao +s); ral =*(const uint4*)(Al+ao +s);
      rbh0=*(const uint4*)(Bh+bo0+s); rbl0=*(const uint4*)(Bl+bo0+s);
      rbh1=*(const uint4*)(Bh+bo1+s); rbl1=*(const uint4*)(Bl+bo1+s);
    }
    bf16x8 afh[2], afl[2], bfh[4], bfl[4];
    #pragma unroll
    for(int mi=0;mi<2;mi++){
      const int o = (wm+mi*16+ml)*32 + quad*8;
      afh[mi] = *(const bf16x8*)&AsH[o];
      afl[mi] = *(const bf16x8*)&AsL[o];
    }
    #pragma unroll
    for(int ni=0;ni<4;ni++){
      const int o = (wn+ni*16+ml)*32 + quad*8;
      bfh[ni] = *(const bf16x8*)&BsH[o];
      bfl[ni] = *(const bf16x8*)&BsL[o];
    }
    #pragma unroll
    for(int mi=0;mi<2;mi++)
      #pragma unroll
      for(int ni=0;ni<4;ni++){
        acc[mi][ni] = __builtin_amdgcn_mfma_f32_16x16x32_bf16(afh[mi], bfh[ni], acc[mi][ni], 0,0,0);
        acc[mi][ni] = __builtin_amdgcn_mfma_f32_16x16x32_bf16(afh[mi], bfl[ni], acc[mi][ni], 0,0,0);
        acc[mi][ni] = __builtin_amdgcn_mfma_f32_16x16x32_bf16(afl[mi], bfh[ni], acc[mi][ni], 0,0,0);
      }
  }
  #pragma unroll
  for(int mi=0;mi<2;mi++){
    const int rbase = m0 + wm + mi*16 + quad*4;
    #pragma unroll
    for(int ni=0;ni<4;ni++){
      const int col = n0 + wn + ni*16 + ml;
      if(SK==1){
        const float bv = bias ? bias[col] : 0.f;
        #pragma unroll
        for(int r=0;r<4;r++){
          float v = acc[mi][ni][r]*scale + bv;
          if(RELU) v = fmaxf(v, 0.f);
          const size_t idx = (size_t)(rbase + r)*ldc + col;
          if(outh){ u16 h, l; split2(v, h, l); outh[idx] = h; outl[idx] = l; }
          if(outf) outf[idx] = v;
        }
      }else{
        #pragma unroll
        for(int r=0;r<4;r++)
          part[((size_t)blockIdx.z*M + rbase + r)*ldc + col] = acc[mi][ni][r];
      }
    }
  }
}

// ============================================================================
// 128x128-tile split-bf16 GEMM (fp32-class). Reg-staged + XCD swizzle.
// ============================================================================
__global__ __launch_bounds__(256)
void gemm3_128(const u16* __restrict__ Ah, const u16* __restrict__ Al, int lda,
               const u16* __restrict__ Bh, const u16* __restrict__ Bl, int ldb,
               const float* __restrict__ bias, float scale,
               float* __restrict__ outf, int K, int ldc)
{
  __shared__ __align__(16) u16 AsH[128*32];
  __shared__ __align__(16) u16 AsL[128*32];
  __shared__ __align__(16) u16 BsH[128*32];
  __shared__ __align__(16) u16 BsL[128*32];
  const int tid = threadIdx.x, lane = tid&63, wave = tid>>6;
  int bxs, bys; xcd_swizzle(bxs, bys);
  const int m0 = bys*128, n0 = bxs*128;
  const int wm = (wave>>1)*64, wn = (wave&1)*64;
  const int ml = lane&15, quad = lane>>4;
  const size_t ao0 = (size_t)(m0+(tid>>2))*lda    + (tid&3)*8;
  const size_t ao1 = (size_t)(m0+64+(tid>>2))*lda + (tid&3)*8;
  const size_t bo0 = (size_t)(n0+(tid>>2))*ldb    + (tid&3)*8;
  const size_t bo1 = (size_t)(n0+64+(tid>>2))*ldb + (tid&3)*8;

  f32x4 acc[4][4];
  #pragma unroll
  for(int i=0;i<4;i++)
    #pragma unroll
    for(int j=0;j<4;j++) acc[i][j] = (f32x4){0.f,0.f,0.f,0.f};

  uint4 rah0=*(const uint4*)(Ah+ao0), ral0=*(const uint4*)(Al+ao0);
  uint4 rah1=*(const uint4*)(Ah+ao1), ral1=*(const uint4*)(Al+ao1);
  uint4 rbh0=*(const uint4*)(Bh+bo0), rbl0=*(const uint4*)(Bl+bo0);
  uint4 rbh1=*(const uint4*)(Bh+bo1), rbl1=*(const uint4*)(Bl+bo1);
  for(int k0=0;k0<K;k0+=32){
    __syncthreads();
    *(uint4*)&AsH[tid*8]       = rah0;
    *(uint4*)&AsH[(256+tid)*8] = rah1;
    *(uint4*)&AsL[tid*8]       = ral0;
    *(uint4*)&AsL[(256+tid)*8] = ral1;
    *(uint4*)&BsH[tid*8]       = rbh0;
    *(uint4*)&BsH[(256+tid)*8] = rbh1;
    *(uint4*)&BsL[tid*8]       = rbl0;
    *(uint4*)&BsL[(256+tid)*8] = rbl1;
    __syncthreads();
    if(k0+32<K){
      const int s = k0+32;
      rah0=*(const uint4*)(Ah+ao0+s); ral0=*(const uint4*)(Al+ao0+s);
      rah1=*(const uint4*)(Ah+ao1+s); ral1=*(const uint4*)(Al+ao1+s);
      rbh0=*(const uint4*)(Bh+bo0+s); rbl0=*(const uint4*)(Bl+bo0+s);
      rbh1=*(const uint4*)(Bh+bo1+s); rbl1=*(const uint4*)(Bl+bo1+s);
    }
    bf16x8 afh[4], afl[4], bfh[4], bfl[4];
    #pragma unroll
    for(int mi=0;mi<4;mi++){
      const int o = (wm+mi*16+ml)*32 + quad*8;
      afh[mi] = *(const bf16x8*)&AsH[o];
      afl[mi] = *(const bf16x8*)&AsL[o];
    }
    #pragma unroll
    for(int ni=0;ni<4;ni++){
      const int o = (wn+ni*16+ml)*32 + quad*8;
      bfh[ni] = *(const bf16x8*)&BsH[o];
      bfl[ni] = *(const bf16x8*)&BsL[o];
    }
    #pragma unroll
    for(int mi=0;mi<4;mi++)
      #pragma unroll
      for(int ni=0;ni<4;ni++){
        acc[mi][ni] = __builtin_amdgcn_mfma_f32_16x16x32_bf16(afh[mi], bfh[ni], acc[mi][ni], 0,0,0);
        acc[mi][ni] = __builtin_amdgcn_mfma_f32_16x16x32_bf16(afh[mi], bfl[ni], acc[mi][ni], 0,0,0);
        acc[mi][ni] = __builtin_amdgcn_mfma_f32_16x16x32_bf16(afl[mi], bfh[ni], acc[mi][ni], 0,0,0);
      }
  }
  #pragma unroll
  for(int mi=0;mi<4;mi++){
    const int rbase = m0 + wm + mi*16 + quad*4;
    #pragma unroll
    for(int ni=0;ni<4;ni++){
      const int col = n0 + wn + ni*16 + ml;
      const float bv = bias ? bias[col] : 0.f;
      #pragma unroll
      for(int r=0;r<4;r++){
        const float v = acc[mi][ni][r]*scale + bv;
        outf[(size_t)(rbase + r)*ldc + col] = v;
      }
    }
  }
}

// ============================================================================
// reduce SK fp32 partials + bias/act -> split-bf16 / bf16 / fp32 outputs.
// Optional fused row-dot: bvout[row] = dot(bqv, rowvals)/32 (block == 1 row).
// ============================================================================
template<bool RELU, int SK>
__global__ __launch_bounds__(256)
void reduce_epi(const float* __restrict__ part, const float* __restrict__ bias,
                float scale, u16* __restrict__ outh, u16* __restrict__ outl,
                u16* __restrict__ outb, float* __restrict__ outf,
                size_t MN, int N,
                const float* __restrict__ bqv, float* __restrict__ bvout)
{
  __shared__ float buf[4];
  const int tid = threadIdx.x;
  const size_t i = ((size_t)blockIdx.x*256 + tid)*4;
  float4 s = *(const float4*)(part + i);
  #pragma unroll
  for(int z=1; z<SK; z++){
    const float4 t = *(const float4*)(part + (size_t)z*MN + i);
    s.x += t.x; s.y += t.y; s.z += t.z; s.w += t.w;
  }
  const int col = (int)(i % (size_t)N);
  float4 bv = bias ? *(const float4*)(bias + col) : (float4){0.f,0.f,0.f,0.f};
  float v[4] = { s.x*scale + bv.x, s.y*scale + bv.y, s.z*scale + bv.z, s.w*scale + bv.w };
  if(RELU){
    #pragma unroll
    for(int j=0;j<4;j++) v[j] = fmaxf(v[j], 0.f);
  }
  if(outh){
    ushort4 h4, l4;
    split2(v[0], h4.x, l4.x); split2(v[1], h4.y, l4.y);
    split2(v[2], h4.z, l4.z); split2(v[3], h4.w, l4.w);
    *(ushort4*)(outh + i) = h4;
    *(ushort4*)(outl + i) = l4;
  }
  if(outb){
    ushort4 b4;
    b4.x=f2bf(v[0]); b4.y=f2bf(v[1]); b4.z=f2bf(v[2]); b4.w=f2bf(v[3]);
    *(ushort4*)(outb + i) = b4;
  }
  if(outf) *(float4*)(outf + i) = (float4){v[0],v[1],v[2],v[3]};
  if(bvout){   // uniform branch; block == one row (N==1024, 256 thr x 4)
    const float4 q = *(const float4*)(bqv + col);
    float d = q.x*v[0] + q.y*v[1] + q.z*v[2] + q.w*v[3];
    d = bredsum(d, buf, tid);
    if(tid==0) bvout[blockIdx.x] = d * 0.03125f;
  }
}

// ============================================================================
// Fused weight prep: all transposes + split conversions in ONE launch.
// ============================================================================
DEV void dev_tsplit(const float* in, u16* oh, u16* ol, int R, int C,
                    int bx, int by, int tid, float (*tile)[33])
{
  const int tx = tid & 31, ty = tid >> 5;
  #pragma unroll
  for(int i=0;i<32;i+=8)
    tile[ty+i][tx] = in[(size_t)(by*32+ty+i)*C + bx*32 + tx];
  __syncthreads();
  #pragma unroll
  for(int i=0;i<32;i+=8){
    const float v = tile[tx][ty+i];
    u16 h, l; split2(v, h, l);
    const size_t o = (size_t)(bx*32+ty+i)*R + by*32 + tx;
    oh[o] = h; if(ol) ol[o] = l;
  }
}
__global__ __launch_bounds__(256)
void prep_weights(const float* __restrict__ Wk, const float* __restrict__ W1,
                  const float* __restrict__ W2, const float* __restrict__ Wv,
                  const float* __restrict__ Wq,
                  u16* __restrict__ WkvTh, u16* __restrict__ WkTl,
                  u16* __restrict__ W1Th,  u16* __restrict__ W1Tl,
                  u16* __restrict__ W2Th,  u16* __restrict__ W2Tl,
                  u16* __restrict__ WqTh,
                  u16* __restrict__ Wqh,   u16* __restrict__ Wql)
{
  __shared__ float tile[32][33];
  const int id = blockIdx.x, tid = threadIdx.x;
  if(id < 1024){
    dev_tsplit(Wk, WkvTh, WkTl, 1024, 1024, id&31, id>>5, tid, tile);
  }else if(id < 3072){
    const int l = id - 1024;
    dev_tsplit(W1, W1Th, W1Tl, 2048, 1024, l&31, l>>5, tid, tile);
  }else if(id < 4096){
    const int l = id - 3072;
    dev_tsplit(W2, W2Th, W2Tl, 1024, 1024, l&31, l>>5, tid, tile);
  }else if(id < 5120){
    const int l = id - 4096;
    dev_tsplit(Wv, WkvTh + 1024*1024, nullptr, 1024, 1024, l&31, l>>5, tid, tile);
  }else if(id < 6144){
    const int l = id - 5120;
    dev_tsplit(Wq, WqTh, nullptr, 1024, 1024, l&31, l>>5, tid, tile);
  }else{
    const int l = id - 6144;
    const int i = l*256 + tid;
    const float4 v = ((const float4*)Wq)[i];
    ushort4 h4, l4;
    split2(v.x, h4.x, l4.x); split2(v.y, h4.y, l4.y);
    split2(v.z, h4.z, l4.z); split2(v.w, h4.w, l4.w);
    ((ushort4*)Wqh)[i] = h4; ((ushort4*)Wql)[i] = l4;
  }
}

// ============================================================================
// Fused LayerNorms: blocks [0,8192) = input rows -> xh/xl (stride 1024);
// blocks [8192,8704) = edge rows (mu + exp(lsig)*noise) -> cath/catl (2048).
// ============================================================================
__global__ __launch_bounds__(256)
void ln_all(const float* __restrict__ in, const float* __restrict__ g,
            const float* __restrict__ bb, u16* __restrict__ outh,
            u16* __restrict__ outl,
            const float* __restrict__ noise, const float* __restrict__ mu,
            const float* __restrict__ lsig, const float* __restrict__ ge,
            const float* __restrict__ be, u16* __restrict__ cath,
            u16* __restrict__ catl)
{
  __shared__ float buf[4];
  const int tid = threadIdx.x;
  const bool edge = blockIdx.x >= 8192;
  const int row = edge ? (blockIdx.x - 8192) : blockIdx.x;
  float v0,v1,v2,v3;
  if(!edge){
    const float4 xv = ((const float4*)(in + (size_t)row*1024))[tid];
    v0=xv.x; v1=xv.y; v2=xv.z; v3=xv.w;
  }else{
    const float4 nv  = ((const float4*)(noise + (size_t)row*1024))[tid];
    const float4 muv = ((const float4*)mu)[tid];
    const float4 lsv = ((const float4*)lsig)[tid];
    v0 = muv.x + expf(lsv.x)*nv.x;
    v1 = muv.y + expf(lsv.y)*nv.y;
    v2 = muv.z + expf(lsv.z)*nv.z;
    v3 = muv.w + expf(lsv.w)*nv.w;
  }
  float s  = bredsum(v0+v1+v2+v3, buf, tid);
  float s2 = bredsum(v0*v0+v1*v1+v2*v2+v3*v3, buf, tid);
  const float mean = s * (1.f/1024.f);
  const float var  = s2 * (1.f/1024.f) - mean*mean;
  const float rs   = 1.f / sqrtf(var + 1e-5f);
  const float4 gv = ((const float4*)(edge?ge:g))[tid];
  const float4 bv = ((const float4*)(edge?be:bb))[tid];
  float o0 = (v0-mean)*rs*gv.x + bv.x;
  float o1 = (v1-mean)*rs*gv.y + bv.y;
  float o2 = (v2-mean)*rs*gv.z + bv.z;
  float o3 = (v3-mean)*rs*gv.w + bv.w;
  ushort4 oh, ol;
  split2(o0, oh.x, ol.x); split2(o1, oh.y, ol.y);
  split2(o2, oh.z, ol.z); split2(o3, oh.w, ol.w);
  u16* ph = edge ? cath : outh;
  u16* pl = edge ? catl : outl;
  const int ostride = edge ? 2048 : 1024;
  ((ushort4*)(ph + (size_t)row*ostride))[tid] = oh;
  ((ushort4*)(pl + (size_t)row*ostride))[tid] = ol;
}

// ============================================================================
// softmax(8192)+eps+renorm + top-k_n -> (idx, weight) pairs. 1 block/row.
// ============================================================================
#define SWZ(i) ((i) ^ (((((unsigned)(i))>>5)&7u)<<2))
__global__ __launch_bounds__(256)
void softmax_topk_a(const float* __restrict__ dots, const int* __restrict__ knp,
                    int* __restrict__ tidx, float* __restrict__ tw)
{
  const int NC = 8192;
  __shared__ __align__(16) uint32_t us[8192];
  __shared__ float fbuf[4];
  __shared__ int ibuf[4];
  __shared__ int scan[256];
  __shared__ uint32_t hist[256];
  __shared__ uint32_t bcast;
  __shared__ int slot_ctr;
  const int row = blockIdx.x, tid = threadIdx.x;
  const int lane = tid & 63, wave = tid >> 6;
  const float* x = dots + (size_t)row * NC;

  float mx = -3.4e38f;
  #pragma unroll
  for(int it=0; it<8; ++it){
    const int i = (tid + it*256)*4;
    const float4 f = *(const float4*)(x + i);
    mx = fmaxf(fmaxf(mx, fmaxf(f.x,f.y)), fmaxf(f.z,f.w));
    uint4 u; u.x=fmap(f.x); u.y=fmap(f.y); u.z=fmap(f.z); u.w=fmap(f.w);
    *(uint4*)&us[SWZ(i)] = u;
  }
  mx = bredmax(mx, fbuf, tid);

  float se = 0.f;
  #pragma unroll
  for(int it=0; it<8; ++it){
    const int i = (tid + it*256)*4;
    const uint4 u = *(const uint4*)&us[SWZ(i)];
    se += expf(funmap(u.x)-mx) + expf(funmap(u.y)-mx)
        + expf(funmap(u.z)-mx) + expf(funmap(u.w)-mx);
  }
  se = bredsum(se, fbuf, tid);
  const float T = 1.f + (float)NC * 1e-8f;

  const int k = knp[0];
  const int base = tid*32;

  uint32_t prefix = 0;
  int remaining = k;
  #pragma unroll
  for(int shift=24; shift>=0; shift-=8){
    hist[tid] = 0;
    __syncthreads();
    const uint32_t himask = (shift==24) ? 0u : (0xFFFFFFFFu << (shift+8));
    #pragma unroll
    for(int j=0;j<32;j+=4){
      const uint4 u4 = *(const uint4*)&us[SWZ(base+j)];
      const uint32_t uu[4] = {u4.x,u4.y,u4.z,u4.w};
      #pragma unroll
      for(int t=0;t<4;t++)
        if((uu[t] & himask) == prefix) atomicAdd(&hist[(uu[t]>>shift)&255u], 1u);
    }
    __syncthreads();
    if(wave==0){
      const uint32_t h0=hist[4*lane], h1=hist[4*lane+1],
                     h2=hist[4*lane+2], h3=hist[4*lane+3];
      const uint32_t s3=h3, s2=h2+s3, s1=h1+s2, s0=h0+s1;
      uint32_t tsum = s0;
      #pragma unroll
      for(int o=1;o<64;o<<=1){
        const uint32_t vv = __shfl_down(tsum, o);
        if(lane + o < 64) tsum += vv;
      }
      const uint32_t excl = tsum - s0;
      const uint32_t r = (uint32_t)remaining;
      int cand = -1; uint32_t gsel = 0;
      if     (s3+excl >= r){ cand = 4*lane+3; gsel = excl; }
      else if(s2+excl >= r){ cand = 4*lane+2; gsel = s3+excl; }
      else if(s1+excl >= r){ cand = 4*lane+1; gsel = s2+excl; }
      else if(s0+excl >= r){ cand = 4*lane+0; gsel = s1+excl; }
      int bestc = cand; uint32_t bestg = gsel;
      #pragma unroll
      for(int o=32;o;o>>=1){
        const int oc = __shfl_xor(bestc, o);
        const uint32_t og = __shfl_xor(bestg, o);
        if(oc > bestc){ bestc = oc; bestg = og; }
      }
      if(lane==0) bcast = (uint32_t)bestc;
      remaining -= (int)bestg;
    }
    __syncthreads();
    prefix |= bcast << shift;
  }
  const uint32_t uth = prefix;

  int gt = 0, eq = 0;
  #pragma unroll
  for(int j=0;j<32;j+=4){
    const uint4 u4 = *(const uint4*)&us[SWZ(base+j)];
    gt += (u4.x>uth)+(u4.y>uth)+(u4.z>uth)+(u4.w>uth);
    eq += (u4.x==uth)+(u4.y==uth)+(u4.z==uth)+(u4.w==uth);
  }
  const int c1 = bredsumi(gt, ibuf, tid);
  __syncthreads();
  scan[tid] = eq;
  __syncthreads();
  #pragma unroll
  for(int o=1;o<256;o<<=1){
    int t = (tid>=o) ? scan[tid-o] : 0;
    __syncthreads();
    scan[tid] += t;
    __syncthreads();
  }
  int eq_rank = scan[tid] - eq;
  const int budget = k - c1;
  if(tid==0) slot_ctr = 0;
  __syncthreads();
  #pragma unroll 2
  for(int j=0;j<32;j+=4){
    const uint4 u4 = *(const uint4*)&us[SWZ(base+j)];
    const uint32_t uu[4] = {u4.x,u4.y,u4.z,u4.w};
    #pragma unroll
    for(int t=0;t<4;t++){
      const uint32_t u = uu[t];
      bool sel = (u > uth);
      if(u == uth){ sel = (eq_rank < budget); eq_rank++; }
      if(sel){
        const int s = atomicAdd(&slot_ctr, 1);
        const float f = funmap(u);
        const float w = (expf(f - mx)/se + 1e-8f) / T;
        if(s < 128){ tidx[row*128 + s] = base + j + t; tw[row*128 + s] = w; }
      }
    }
  }
}

// updates[row] = sum_j w_j * v[idx_j] (v bf16) ; split-bf16 into cat[:,1024:]
__global__ __launch_bounds__(256)
void gather_updates(const int* __restrict__ tidx, const float* __restrict__ tw,
                    const int* __restrict__ knp, const u16* __restrict__ v,
                    u16* __restrict__ cath, u16* __restrict__ catl)
{
  __shared__ int   idx_s[128];
  __shared__ float w_s[128];
  const int row = blockIdx.x, tid = threadIdx.x;
  const int kk = knp[0];
  if(tid < 128){
    idx_s[tid] = (tid < kk) ? (tidx[row*128+tid] & 8191) : 0;
    w_s[tid]   = (tid < kk) ? tw[row*128+tid] : 0.f;
  }
  __syncthreads();
  const int c = tid*4;
  float a0=0,a1=0,a2=0,a3=0;
  for(int j=0;j<kk && j<128;j++){
    const ushort4 vv = *(const ushort4*)&v[(size_t)idx_s[j]*1024 + c];
    const float w = w_s[j];
    a0 += w*bf2f(vv.x); a1 += w*bf2f(vv.y); a2 += w*bf2f(vv.z); a3 += w*bf2f(vv.w);
  }
  ushort4 oh, ol;
  split2(a0, oh.x, ol.x); split2(a1, oh.y, ol.y);
  split2(a2, oh.z, ol.z); split2(a3, oh.w, ol.w);
  ((ushort4*)(cath + (size_t)row*2048 + 1024))[tid] = oh;
  ((ushort4*)(catl + (size_t)row*2048 + 1024))[tid] = ol;
}

// ============================================================================
// H: softmax over 512 + top-k_e mask, one WAVE per row (4 rows/block).
// ============================================================================
__global__ __launch_bounds__(256)
void softmax_topk_h_wave(const float* __restrict__ dv, const int* __restrict__ kep,
                         float* __restrict__ H)
{
  const int wave = threadIdx.x >> 6, lane = threadIdx.x & 63;
  const int row = blockIdx.x*4 + wave;
  const float* x = dv + (size_t)row*512 + lane*8;
  const float4 a = *(const float4*)x;
  const float4 b = *(const float4*)(x+4);
  float vals[8] = {a.x,a.y,a.z,a.w,b.x,b.y,b.z,b.w};

  float mx = vals[0];
  #pragma unroll
  for(int j=1;j<8;j++) mx = fmaxf(mx, vals[j]);
  #pragma unroll
  for(int o=32;o;o>>=1) mx = fmaxf(mx, __shfl_xor(mx, o));
  float e[8], se = 0.f;
  #pragma unroll
  for(int j=0;j<8;j++){ e[j] = expf(vals[j]-mx); se += e[j]; }
  #pragma unroll
  for(int o=32;o;o>>=1) se += __shfl_xor(se, o);
  const float inv = 1.f/se;

  const int k = kep[0];
  unsigned int selmask = 0;
  for(int r=0;r<k;r++){
    unsigned long long best = 0;
    #pragma unroll
    for(int j=0;j<8;j++){
      if(!((selmask>>j)&1u)){
        const unsigned long long key =
          ((unsigned long long)fmap(vals[j]) << 9) | (unsigned long long)(511 - (lane*8+j));
        if(key > best) best = key;
      }
    }
    #pragma unroll
    for(int o=32;o;o>>=1){
      const unsigned long long other = __shfl_xor(best, o);
      if(other > best) best = other;
    }
    const int bidx = 511 - (int)(best & 511ull);
    if((bidx>>3) == lane) selmask |= 1u << (bidx & 7);
  }

  float4 o0, o1;
  o0.x = (selmask&  1u) ? e[0]*inv : 0.f;
  o0.y = (selmask&  2u) ? e[1]*inv : 0.f;
  o0.z = (selmask&  4u) ? e[2]*inv : 0.f;
  o0.w = (selmask&  8u) ? e[3]*inv : 0.f;
  o1.x = (selmask& 16u) ? e[4]*inv : 0.f;
  o1.y = (selmask& 32u) ? e[5]*inv : 0.f;
  o1.z = (selmask& 64u) ? e[6]*inv : 0.f;
  o1.w = (selmask&128u) ? e[7]*inv : 0.f;
  float* outp = H + (size_t)row*512 + lane*8;
  *(float4*)outp     = o0;
  *(float4*)(outp+4) = o1;
}

// ============================================================================
extern "C" void kernel_launch(void* const* d_in, const int* in_sizes, int n_in,
                              void* d_out, int out_size, void* d_ws, size_t ws_size,
                              hipStream_t stream)
{
  const float* inputs = (const float*)d_in[0];
  const float* noise  = (const float*)d_in[1];
  const float* emu    = (const float*)d_in[2];
  const float* elsig  = (const float*)d_in[3];
  const float* Wq = (const float*)d_in[4];  const float* bq = (const float*)d_in[5];
  const float* Wk = (const float*)d_in[6];  const float* bk = (const float*)d_in[7];
  const float* Wv = (const float*)d_in[8];  const float* bv = (const float*)d_in[9];
  const float* W1 = (const float*)d_in[10]; const float* b1 = (const float*)d_in[11];
  const float* W2 = (const float*)d_in[12]; const float* b2 = (const float*)d_in[13];
  const float* g_in = (const float*)d_in[14]; const float* b_in = (const float*)d_in[15];
  const float* g_e  = (const float*)d_in[16]; const float* b_e  = (const float*)d_in[17];
  const int* knp = (const int*)d_in[18];
  const int* kep = (const int*)d_in[19];

  float* out = (float*)d_out;
  float* out_edges = out;                             // 512*1024
  float* out_H     = out + 512*1024;                  // 8192*512
  float* out_dots  = out + 512*1024 + 8192*512;       // 512*8192

  // ---- workspace (~112 MB peak, stream-ordered reuse) ----
  char* p = (char*)d_ws;
  const size_t MB = 1024ull*1024;
  u16* xh = (u16*)(p + 0*MB);            // x split, live to the end (dots_v)
  u16* xl = (u16*)(p + 16*MB);
  u16* kb = (u16*)(p + 32*MB);           // k bf16, dead after dots GEMM
  u16* vb = (u16*)(p + 48*MB);           // v bf16, dead after gather
  float* dotsvf = (float*)(p + 32*MB);   // dots_v fp32 (reuses kb region)
  // weights [64,88)
  u16* WkvTh = (u16*)(p + 64*MB);        // stacked [WkT;WvT], 2048x1024 (4MB)
  u16* WkTl  = (u16*)(p + 68*MB);
  u16* WqTh  = (u16*)(p + 70*MB);
  u16* Wqh   = (u16*)(p + 72*MB);  u16* Wql  = (u16*)(p + 74*MB);   // raw (no T)
  u16* W1Th  = (u16*)(p + 76*MB);  u16* W1Tl = (u16*)(p + 80*MB);
  u16* W2Th  = (u16*)(p + 84*MB);  u16* W2Tl = (u16*)(p + 86*MB);
  // small [88,102)
  u16* cath = (u16*)(p + 88*MB);  u16* catl = (u16*)(p + 90*MB);
  u16* qmb  = (u16*)(p + 92*MB);
  u16* h1h  = (u16*)(p + 93*MB);  u16* h1l  = (u16*)(p + 94*MB);
  u16* eoh  = (u16*)(p + 95*MB);  u16* eol  = (u16*)(p + 96*MB);
  u16* k2h  = (u16*)(p + 97*MB);  u16* k2l  = (u16*)(p + 98*MB);
  u16* Gth  = (u16*)(p + 99*MB);  u16* Gtl  = (u16*)(p + 100*MB);
  int*   tidx  = (int*)  (p + 101*MB);
  float* tw    = (float*)(p + 101*MB + 256*1024);
  float* biasv = (float*)(p + 101*MB + 512*1024);
  float* part  = (float*)(p + 104*MB);   // split-K partials: 4*512*1024*4 = 8MB

  // (memset of tidx/tw removed: softmax_topk_a provably writes slots [0,k)
  //  each run, and gather_updates reads only [0,min(k,128)).)

  // fused weight prep
  prep_weights<<<7168,256,0,stream>>>(Wk, W1, W2, Wv, Wq,
                                      WkvTh, WkTl, W1Th, W1Tl, W2Th, W2Tl,
                                      WqTh, Wqh, Wql);
  // fused layernorms
  ln_all<<<8704,256,0,stream>>>(inputs, g_in, b_in, xh, xl,
                                noise, emu, elsig, g_e, b_e, cath, catl);

  const size_t MN = 512ull*1024;
  // --- dots chain (plain bf16; selection-tolerant) ---
  // k|v = relu(x@{Wk,Wv}+b): 256x256-tile pipelined kernel, grid (2048/256, 8192/256)
  gemm_kv_256<<<dim3(8,32),512,0,stream>>>(xh,1024, WkvTh,1024, bk, bv,
                                           kb, vb, 1024);
  // qm = relu(cat@Wq+bq): M=512 -> 64-tile split-K4, grid (8,8,4)
  gemm1_64<false,4><<<dim3(8,8,4),256,0,stream>>>(cath,2048, WqTh,1024, nullptr, 1.f,
                                                  nullptr,nullptr, part, 1024,1024,512);
  reduce_epi<true,4><<<512,256,0,stream>>>(part, bq, 1.f, nullptr,nullptr, qmb,nullptr,
                                           MN, 1024, nullptr, nullptr);
  // dots = qm@k^T / 32 -> fp32 d_out: grid (8192/128, 512/128)
  gemm1_128<false><<<dim3(64,4),256,0,stream>>>(qmb,1024, kb,1024, nullptr, 0.03125f,
                                                nullptr,out_dots, 1024,8192);
  softmax_topk_a<<<512,256,0,stream>>>(out_dots, knp, tidx, tw);
  gather_updates<<<512,256,0,stream>>>(tidx, tw, knp, vb, cath, catl);

  // --- edges + H chain (split-bf16, fp32-class), all M=512 -> split-K4 ---
  gemm3_64<false,4><<<dim3(8,8,4),256,0,stream>>>(cath,catl,2048, W1Th,W1Tl,2048,
                                                  nullptr,1.f, nullptr,nullptr,nullptr,
                                                  part, 2048,1024,512);
  reduce_epi<true,4><<<512,256,0,stream>>>(part, b1, 1.f, h1h,h1l, nullptr,nullptr,
                                           MN, 1024, nullptr, nullptr);
  gemm3_64<false,4><<<dim3(8,8,4),256,0,stream>>>(h1h,h1l,1024, W2Th,W2Tl,1024,
                                                  nullptr,1.f, nullptr,nullptr,nullptr,
                                                  part, 1024,1024,512);
  reduce_epi<false,4><<<512,256,0,stream>>>(part, b2, 1.f, eoh,eol, nullptr,out_edges,
                                            MN, 1024, nullptr, nullptr);
  // k2 = relu(edges@Wk+bk); fused bias_v = dot(bq,k2_row)/32 per row
  gemm3_64<false,4><<<dim3(8,8,4),256,0,stream>>>(eoh,eol,1024, WkvTh,WkTl,1024,
                                                  nullptr,1.f, nullptr,nullptr,nullptr,
                                                  part, 1024,1024,512);
  reduce_epi<true,4><<<512,256,0,stream>>>(part, bk, 1.f, k2h,k2l, nullptr,nullptr,
                                           MN, 1024, bq, biasv);
  // Gt[m,e] = sum_d k2[m,d]*Wq[e,d]
  gemm3_64<false,4><<<dim3(8,8,4),256,0,stream>>>(k2h,k2l,1024, Wqh,Wql,1024,
                                                  nullptr,1.f, nullptr,nullptr,nullptr,
                                                  part, 1024,1024,512);
  reduce_epi<false,4><<<512,256,0,stream>>>(part, nullptr, 1.f, Gth,Gtl, nullptr,nullptr,
                                            MN, 1024, nullptr, nullptr);
  // dots_v = x@Gt^T / 32 + biasv : 128-tile, grid (512/128, 8192/128)
  gemm3_128<<<dim3(4,64),256,0,stream>>>(xh,xl,1024, Gth,Gtl,1024,
                                         biasv, 0.03125f, dotsvf, 1024,512);
  softmax_topk_h_wave<<<2048,256,0,stream>>>(dotsvf, kep, out_H);
}